// Round 1
// baseline (1257.451 us; speedup 1.0000x reference)
//
#include <hip/hip_runtime.h>
#include <hip/hip_bf16.h>
#include <math.h>

// Problem dims
#define B_ 16
#define T_ 1024
#define P_ 48
#define S_ 12
#define A_ 24
#define D_ 768
#define D4_ 3072
#define G3_ 2304
#define RV_ (B_*T_)      // 16384 video rows
#define RP_ (B_*P_)      // 768 para rows
#define RA_ (B_*S_*A_)   // 4608 answer rows
#define RH_ (B_*S_)      // 192 (b,s) rows

typedef float f32x4 __attribute__((ext_vector_type(4)));
typedef short s16x8 __attribute__((ext_vector_type(8)));

__device__ __forceinline__ unsigned short f2bf(float f) {
  unsigned int u = __float_as_uint(f);
  u += 0x7FFF + ((u >> 16) & 1);   // round-to-nearest-even
  return (unsigned short)(u >> 16);
}
__device__ __forceinline__ unsigned int pk2(float lo, float hi) {
  return (unsigned int)f2bf(lo) | ((unsigned int)f2bf(hi) << 16);
}

// Generic C = act(A[M,K] @ W[K,N] + bias), f32 in/out, bf16 MFMA inside.
// A row-major lda, W row-major [K,N], C row-major ldc. BM=BN=128, BK=32.
// 4 waves, each computes a 64x64 subtile as 4x4 fragments of 16x16x32.
template<int ACT>
__global__ __launch_bounds__(256)
void gemm_f32_bf16(const float* __restrict__ A, int lda,
                   const float* __restrict__ W,
                   const float* __restrict__ bias,
                   float* __restrict__ C, int ldc,
                   int M, int N, int K)
{
  __shared__ short As[128][32];   // As[m][k]
  __shared__ short Bs[128][32];   // Bs[n][k]  (W tile transposed)
  const int tid  = threadIdx.x;
  const int lane = tid & 63;
  const int wid  = tid >> 6;
  const int wm = (wid >> 1) * 64, wn = (wid & 1) * 64;
  const int bm0 = blockIdx.y * 128, bn0 = blockIdx.x * 128;

  f32x4 acc[4][4] = {};

  // A staging: thread -> (row = tid>>1, 16 contiguous k at (tid&1)*16)
  int a_row = tid >> 1;
  int a_kb  = (tid & 1) * 16;
  int a_g   = bm0 + a_row; if (a_g > M - 1) a_g = M - 1;   // clamp (guarded on write)
  const float* Abase = A + (size_t)a_g * lda + a_kb;

  // B staging: thread -> (col = tid&127, 16 k's down the column at (tid>>7)*16)
  int b_col = tid & 127;
  int b_kb  = (tid >> 7) * 16;
  int b_g   = bn0 + b_col; if (b_g > N - 1) b_g = N - 1;

  for (int k0 = 0; k0 < K; k0 += 32) {
    // global loads (before barrier, overlap with previous compute)
    float4 a0 = *(const float4*)(Abase + k0);
    float4 a1 = *(const float4*)(Abase + k0 + 4);
    float4 a2 = *(const float4*)(Abase + k0 + 8);
    float4 a3 = *(const float4*)(Abase + k0 + 12);
    const float* wp = W + (size_t)(k0 + b_kb) * N + b_g;
    float bv[16];
#pragma unroll
    for (int j = 0; j < 16; ++j) bv[j] = wp[(size_t)j * N];

    __syncthreads();   // previous iteration's LDS reads complete
    uint4 pa0, pa1, pb0, pb1;
    pa0.x = pk2(a0.x, a0.y); pa0.y = pk2(a0.z, a0.w);
    pa0.z = pk2(a1.x, a1.y); pa0.w = pk2(a1.z, a1.w);
    pa1.x = pk2(a2.x, a2.y); pa1.y = pk2(a2.z, a2.w);
    pa1.z = pk2(a3.x, a3.y); pa1.w = pk2(a3.z, a3.w);
    *(uint4*)(&As[a_row][a_kb])     = pa0;
    *(uint4*)(&As[a_row][a_kb + 8]) = pa1;
    pb0.x = pk2(bv[0], bv[1]);  pb0.y = pk2(bv[2], bv[3]);
    pb0.z = pk2(bv[4], bv[5]);  pb0.w = pk2(bv[6], bv[7]);
    pb1.x = pk2(bv[8], bv[9]);  pb1.y = pk2(bv[10], bv[11]);
    pb1.z = pk2(bv[12], bv[13]);pb1.w = pk2(bv[14], bv[15]);
    *(uint4*)(&Bs[b_col][b_kb])     = pb0;
    *(uint4*)(&Bs[b_col][b_kb + 8]) = pb1;
    __syncthreads();

    // fragments: lane holds row=lane&15, k=(lane>>4)*8+j (k-contiguous, b128)
    s16x8 af[4], bf[4];
#pragma unroll
    for (int i = 0; i < 4; ++i) {
      af[i] = *(const s16x8*)(&As[wm + i*16 + (lane & 15)][(lane >> 4) * 8]);
      bf[i] = *(const s16x8*)(&Bs[wn + i*16 + (lane & 15)][(lane >> 4) * 8]);
    }
#pragma unroll
    for (int mi = 0; mi < 4; ++mi)
#pragma unroll
      for (int ni = 0; ni < 4; ++ni)
        acc[mi][ni] = __builtin_amdgcn_mfma_f32_16x16x32_bf16(af[mi], bf[ni], acc[mi][ni], 0, 0, 0);
  }

  // epilogue: D mapping col=lane&15, row=(lane>>4)*4+r (m89/m91 verified)
  const int fr = lane & 15, fq = lane >> 4;
#pragma unroll
  for (int ni = 0; ni < 4; ++ni) {
    int col = bn0 + wn + ni * 16 + fr;   // always < N (N multiple of 128 here)
    float bb = bias[col];
#pragma unroll
    for (int mi = 0; mi < 4; ++mi)
#pragma unroll
      for (int r = 0; r < 4; ++r) {
        int row = bm0 + wm + mi * 16 + fq * 4 + r;
        if (row < M) {
          float v = acc[mi][ni][r] + bb;
          if (ACT) v = fmaxf(v, 0.f);
          C[(size_t)row * ldc + col] = v;
        }
      }
  }
}

// softmax over P=48 per batch row
__global__ void softmax_p(const float* __restrict__ ps, float* __restrict__ score) {
  int b = blockIdx.x, lane = threadIdx.x;
  float v = (lane < P_) ? ps[b * P_ + lane] : -INFINITY;
  float m = v;
  for (int o = 32; o > 0; o >>= 1) m = fmaxf(m, __shfl_xor(m, o));
  float e = (lane < P_) ? __expf(v - m) : 0.f;
  float s = e;
  for (int o = 32; o > 0; o >>= 1) s += __shfl_xor(s, o);
  if (lane < P_) score[b * P_ + lane] = e / s;
}

// in-place inclusive cumsum over T per (b,d); coalesced across threads
__global__ void cumsum_t(float* __restrict__ v) {
  int d = blockIdx.x * 256 + threadIdx.x;
  int b = blockIdx.y;
  float* p = v + (size_t)b * T_ * D_ + d;
  float acc = 0.f;
  for (int t = 0; t < T_; ++t) {
    acc += p[(size_t)t * D_];
    p[(size_t)t * D_] = acc;
  }
}

// text_seg[b,d] = sum_p score * para_t
__global__ void weighted_sum_para(const float* __restrict__ para_t, const float* __restrict__ score,
                                  float* __restrict__ out) {
  int d = blockIdx.x * 256 + threadIdx.x;
  int b = blockIdx.y;
  float acc = 0.f;
  for (int p = 0; p < P_; ++p)
    acc += score[b * P_ + p] * para_t[((size_t)b * P_ + p) * D_ + d];
  out[b * D_ + d] = acc;
}

// video_seg from inclusive cumsum C: sum[0:e]=C[e-1], first=C[s]-C[s-1]
__global__ void video_seg_k(const float* __restrict__ C, const float* __restrict__ score,
                            const int* __restrict__ starts, const int* __restrict__ ends,
                            float* __restrict__ out) {
  int d = blockIdx.x * 256 + threadIdx.x;
  int b = blockIdx.y;
  const float* Cb = C + (size_t)b * T_ * D_;
  float acc = 0.f;
  for (int p = 0; p < P_; ++p) {
    int s = starts[b * P_ + p], e = ends[b * P_ + p];
    float sc = score[b * P_ + p];
    float cs = (s > 0) ? Cb[(size_t)(s - 1) * D_ + d] : 0.f;
    float val;
    if (s >= e) val = Cb[(size_t)s * D_ + d] - cs;            // first row
    else        val = (Cb[(size_t)(e - 1) * D_ + d] - cs) / (float)(e - s);
    acc += sc * val;
  }
  out[b * D_ + d] = acc;
}

// fill inputs cols [0:768)=video_seg, [768:1536)=text_seg, += q on [1536:2304)
__global__ void build_inputs_k(float* __restrict__ inputs, const float* __restrict__ vseg,
                               const float* __restrict__ tseg, const float* __restrict__ q) {
  int idx = blockIdx.x * 256 + threadIdx.x;     // over RA_*D_
  int m = idx / D_, d = idx % D_;
  int b = m / (S_ * A_);
  float* row = inputs + (size_t)m * D4_;
  row[d]          = vseg[b * D_ + d];
  row[D_ + d]     = tseg[b * D_ + d];
  row[2 * D_ + d] += q[b * D_ + d];
}

// H[b,s] = s==0 ? state0 : x_all[b,s-1,label[b,s-1]]
__global__ void gather_h_k(const float* __restrict__ xall, const int* __restrict__ label,
                           const float* __restrict__ state0, float* __restrict__ H) {
  int idx = blockIdx.x * 256 + threadIdx.x;     // RH_*D_
  int m = idx / D_, d = idx % D_;
  int b = m / S_, s = m % S_;
  float v;
  if (s == 0) v = state0[d];
  else {
    int lab = label[b * S_ + (s - 1)];
    v = xall[(((size_t)b * S_ + (s - 1)) * A_ + lab) * D_ + d];
  }
  H[idx] = v;
}

// GRU gates: hnew = (1-z)*n + z*h
__global__ void gru_gates_k(const float* __restrict__ gi, const float* __restrict__ gh,
                            const float* __restrict__ H, float* __restrict__ hnew) {
  int idx = blockIdx.x * 256 + threadIdx.x;     // RA_*D_
  int m = idx / D_, d = idx % D_;
  int bs = m / A_;
  const float* gim = gi + (size_t)m * G3_;
  const float* ghm = gh + (size_t)bs * G3_;
  float ir = gim[d], iz = gim[D_ + d], inn = gim[2 * D_ + d];
  float hr = ghm[d], hz = ghm[D_ + d], hn = ghm[2 * D_ + d];
  float r = 1.f / (1.f + __expf(-(ir + hr)));
  float z = 1.f / (1.f + __expf(-(iz + hz)));
  float n = tanhf(inn + r * hn);
  float h = H[(size_t)bs * D_ + d];
  hnew[idx] = (1.f - z) * n + z * h;
}

// logits[m] = dot(t1[m,:], wq2[:,0]) + bq2 ; one wave per row
__global__ void logits_k(const float* __restrict__ t1, const float* __restrict__ wq2,
                         const float* __restrict__ bq2, float* __restrict__ logits) {
  int wid = threadIdx.x >> 6, lane = threadIdx.x & 63;
  int m = blockIdx.x * 4 + wid;
  const float* row = t1 + (size_t)m * D_;
  float acc = 0.f;
  for (int j = lane; j < D_; j += 64) acc += row[j] * wq2[j];
  for (int o = 32; o > 0; o >>= 1) acc += __shfl_xor(acc, o);
  if (lane == 0) logits[m] = acc + bq2[0];
}

// per-(b,s) NLL over A=24 logits, mean over 192 -> out[0]
__global__ void loss_k(const float* __restrict__ logits, const int* __restrict__ label,
                       float* __restrict__ out) {
  __shared__ float red[256];
  int tid = threadIdx.x;
  float ls = 0.f;
  if (tid < RH_) {
    int b = tid / S_, s = tid % S_;
    const float* lg = logits + ((size_t)b * S_ + s) * A_;
    float mx = -INFINITY;
    for (int a = 0; a < A_; ++a) mx = fmaxf(mx, lg[a]);
    float sum = 0.f;
    for (int a = 0; a < A_; ++a) sum += __expf(lg[a] - mx);
    int lab = label[b * S_ + s];
    ls = (logf(sum) + mx) - lg[lab];
  }
  red[tid] = ls;
  for (int o = 128; o > 0; o >>= 1) {
    __syncthreads();
    if (tid < o) red[tid] += red[tid + o];
  }
  if (tid == 0) out[0] = red[0] / (float)RH_;
}

extern "C" void kernel_launch(void* const* d_in, const int* in_sizes, int n_in,
                              void* d_out, int out_size, void* d_ws, size_t ws_size,
                              hipStream_t stream) {
  (void)in_sizes; (void)n_in; (void)out_size; (void)ws_size;
  const float* video      = (const float*)d_in[0];
  const float* para       = (const float*)d_in[1];
  const float* question   = (const float*)d_in[2];
  const float* a_texts    = (const float*)d_in[3];
  const float* a_buttons  = (const float*)d_in[4];
  const float* paras_score= (const float*)d_in[5];
  const int*   starts     = (const int*)d_in[6];
  const int*   ends       = (const int*)d_in[7];
  const int*   label      = (const int*)d_in[8];
  const float* wv1 = (const float*)d_in[9];  const float* bv1 = (const float*)d_in[10];
  const float* wv2 = (const float*)d_in[11]; const float* bv2 = (const float*)d_in[12];
  const float* wt1 = (const float*)d_in[13]; const float* bt1 = (const float*)d_in[14];
  const float* wt2 = (const float*)d_in[15]; const float* bt2 = (const float*)d_in[16];
  const float* wp1 = (const float*)d_in[17]; const float* bp1 = (const float*)d_in[18];
  const float* wp2 = (const float*)d_in[19]; const float* bp2 = (const float*)d_in[20];
  const float* w_ih= (const float*)d_in[21]; const float* b_ih= (const float*)d_in[22];
  const float* w_hh= (const float*)d_in[23]; const float* b_hh= (const float*)d_in[24];
  const float* wq1 = (const float*)d_in[25]; const float* bq1 = (const float*)d_in[26];
  const float* wq2 = (const float*)d_in[27]; const float* bq2 = (const float*)d_in[28];
  const float* state0 = (const float*)d_in[29];

  float* ws = (float*)d_ws;
  // layout (floats)
  float* hidden = ws;                       // 14,155,776 (reused: MLP hiddens, hidden_p, hnew, t1)
  float* vv     = ws + 14155776;            // 12,582,912 video_v -> cumsum -> later gi (10,616,832)
  float* inputs = ws + 26738688;            // 14,155,776 concat [4608,3072]
  float* xall   = ws + 40894464;            //  3,538,944
  float* sm     = ws + 44433408;            // smalls
  float* score  = sm;                       // 768
  float* para_t = sm + 768;                 // 589,824
  float* tseg   = sm + 590592;              // 12,288
  float* vseg   = sm + 602880;              // 12,288
  float* qh     = sm + 615168;              // 12,288
  float* q      = sm + 627456;              // 12,288
  float* H      = sm + 639744;              // 147,456
  float* gh     = sm + 787200;              // 442,368
  float* logits = sm + 1229568;             // 4,608
  float* gi     = vv;                       // reuse video_v region
  float* hnew   = hidden;                   // [4608,768]
  float* t1     = hidden + 7077888;         // [4608,768]

  dim3 blk(256);

  // 1. score = softmax(paras_score)
  softmax_p<<<B_, 64, 0, stream>>>(paras_score, score);

  // 2. para_t = MLP_t(para)  [768,768]
  gemm_f32_bf16<1><<<dim3(6, 6), blk, 0, stream>>>(para, D_, wt1, bt1, hidden, D_, RP_, D_, D_);
  gemm_f32_bf16<0><<<dim3(6, 6), blk, 0, stream>>>(hidden, D_, wt2, bt2, para_t, D_, RP_, D_, D_);
  // 3. text_seg
  weighted_sum_para<<<dim3(3, B_), blk, 0, stream>>>(para_t, score, tseg);

  // 4. video_v = MLP_v(video)  [16384,768]
  gemm_f32_bf16<1><<<dim3(6, 128), blk, 0, stream>>>(video, D_, wv1, bv1, hidden, D_, RV_, D_, D_);
  gemm_f32_bf16<0><<<dim3(6, 128), blk, 0, stream>>>(hidden, D_, wv2, bv2, vv, D_, RV_, D_, D_);
  // 5. in-place cumsum over T
  cumsum_t<<<dim3(3, B_), blk, 0, stream>>>(vv);
  // 6. video_seg
  video_seg_k<<<dim3(3, B_), blk, 0, stream>>>(vv, score, starts, ends, vseg);

  // 7. q = MLP_t(question)  [16,768]
  gemm_f32_bf16<1><<<dim3(6, 1), blk, 0, stream>>>(question, D_, wt1, bt1, qh, D_, B_, D_, D_);
  gemm_f32_bf16<0><<<dim3(6, 1), blk, 0, stream>>>(qh, D_, wt2, bt2, q, D_, B_, D_, D_);

  // 8. at = MLP_t(a_texts) -> inputs cols [1536:2304)
  gemm_f32_bf16<1><<<dim3(6, 36), blk, 0, stream>>>(a_texts, D_, wt1, bt1, hidden, D_, RA_, D_, D_);
  gemm_f32_bf16<0><<<dim3(6, 36), blk, 0, stream>>>(hidden, D_, wt2, bt2, inputs + 2 * D_, D4_, RA_, D_, D_);
  // 9. ab = MLP_v(a_buttons) -> inputs cols [2304:3072)
  gemm_f32_bf16<1><<<dim3(6, 36), blk, 0, stream>>>(a_buttons, D_, wv1, bv1, hidden, D_, RA_, D_, D_);
  gemm_f32_bf16<0><<<dim3(6, 36), blk, 0, stream>>>(hidden, D_, wv2, bv2, inputs + 3 * D_, D4_, RA_, D_, D_);
  // 10. broadcast seg cols + add q to qa
  build_inputs_k<<<RA_ * D_ / 256, blk, 0, stream>>>(inputs, vseg, tseg, q);

  // 11. hidden_p = relu(inputs @ wp1 + bp1)  [4608,3072]
  gemm_f32_bf16<1><<<dim3(24, 36), blk, 0, stream>>>(inputs, D4_, wp1, bp1, hidden, D4_, RA_, D4_, D4_);
  // 12. x_all = hidden_p @ wp2 + bp2  [4608,768]
  gemm_f32_bf16<0><<<dim3(6, 36), blk, 0, stream>>>(hidden, D4_, wp2, bp2, xall, D_, RA_, D_, D4_);

  // 13. H gather (scan is embarrassingly parallel: h comes from x_all/labels)
  gather_h_k<<<RH_ * D_ / 256, blk, 0, stream>>>(xall, label, state0, H);
  // 14. gi = x_all @ w_ih + b_ih  [4608,2304]
  gemm_f32_bf16<0><<<dim3(18, 36), blk, 0, stream>>>(xall, D_, w_ih, b_ih, gi, G3_, RA_, G3_, D_);
  // 15. gh = H @ w_hh + b_hh  [192,2304]
  gemm_f32_bf16<0><<<dim3(18, 2), blk, 0, stream>>>(H, D_, w_hh, b_hh, gh, G3_, RH_, G3_, D_);
  // 16. gates -> hnew
  gru_gates_k<<<RA_ * D_ / 256, blk, 0, stream>>>(gi, gh, H, hnew);
  // 17. t1 = relu(hnew @ wq1 + bq1)
  gemm_f32_bf16<1><<<dim3(6, 36), blk, 0, stream>>>(hnew, D_, wq1, bq1, t1, D_, RA_, D_, D_);
  // 18. logits (N=1 dot kernel)
  logits_k<<<RA_ / 4, blk, 0, stream>>>(t1, wq2, bq2, logits);
  // 19. loss -> d_out[0]
  loss_k<<<1, blk, 0, stream>>>(logits, label, (float*)d_out);
}

// Round 2
// 972.341 us; speedup vs baseline: 1.2932x; 1.2932x over previous
//
#include <hip/hip_runtime.h>
#include <hip/hip_bf16.h>
#include <math.h>

// Problem dims
#define B_ 16
#define T_ 1024
#define P_ 48
#define S_ 12
#define A_ 24
#define D_ 768
#define D4_ 3072
#define G3_ 2304
#define RV_ (B_*T_)      // 16384 video rows
#define RP_ (B_*P_)      // 768 para rows
#define RA_ (B_*S_*A_)   // 4608 answer rows
#define RH_ (B_*S_)      // 192 (b,s) rows

typedef float f32x4 __attribute__((ext_vector_type(4)));
typedef short s16x8 __attribute__((ext_vector_type(8)));

__device__ __forceinline__ unsigned short f2bf(float f) {
  unsigned int u = __float_as_uint(f);
  u += 0x7FFF + ((u >> 16) & 1);   // RNE
  return (unsigned short)(u >> 16);
}
__device__ __forceinline__ unsigned int pk2(float lo, float hi) {
  return (unsigned int)f2bf(lo) | ((unsigned int)f2bf(hi) << 16);
}
__device__ __forceinline__ float bf2f(unsigned short u) {
  return __uint_as_float(((unsigned int)u) << 16);
}

__device__ __forceinline__ void gload16(const void* g, void* l) {
  __builtin_amdgcn_global_load_lds((const __attribute__((address_space(1))) void*)g,
                                   (__attribute__((address_space(3))) void*)l, 16, 0, 0);
}

// ---------------- m97-structure GEMM: C = act(A_bf16[M,K] @ Wt_bf16[N,K]^T + bias) ----------
// 128x128 tile, BK=32, 4 waves each 64x64. A,Wt staged via global_load_lds width16.
// K % 32 == 0, N % 128 == 0; M arbitrary (source rows clamped, writes guarded).
template<int ACT, int OF32>
__global__ __launch_bounds__(256)
void gemm_bf16(const unsigned short* __restrict__ A,
               const unsigned short* __restrict__ Wt,
               const float* __restrict__ bias,
               void* __restrict__ Cout, int ldc,
               int M, int N, int K)
{
  __shared__ __align__(16) unsigned short As[4096];   // [128][32]
  __shared__ __align__(16) unsigned short Bs[4096];
  const int tid  = threadIdx.x;
  const int lane = tid & 63;
  const int wid  = tid >> 6;
  const int wm = (wid >> 1) * 64, wn = (wid & 1) * 64;
  const int bm0 = blockIdx.y * 128, bn0 = blockIdx.x * 128;

  // per-lane global sources (row-chunk layout matches linear LDS dest: byte = row*64 + (lane&3)*16)
  int arow = wid * 16 + (lane >> 2);
  int ar0 = bm0 + arow;       if (ar0 > M - 1) ar0 = M - 1;
  int ar1 = bm0 + arow + 64;  if (ar1 > M - 1) ar1 = M - 1;
  const char* gA0 = (const char*)(A + (size_t)ar0 * K) + (lane & 3) * 16;
  const char* gA1 = (const char*)(A + (size_t)ar1 * K) + (lane & 3) * 16;
  const char* gB0 = (const char*)(Wt + (size_t)(bn0 + arow) * K) + (lane & 3) * 16;
  const char* gB1 = (const char*)(Wt + (size_t)(bn0 + arow + 64) * K) + (lane & 3) * 16;
  // wave-uniform LDS bases (each lane writes base + lane*16)
  unsigned short* lA0 = As + wid * 512;
  unsigned short* lA1 = As + 2048 + wid * 512;
  unsigned short* lB0 = Bs + wid * 512;
  unsigned short* lB1 = Bs + 2048 + wid * 512;

  f32x4 acc[4][4] = {};
  const int fr = lane & 15, fq = lane >> 4;

  for (int kb = 0; kb < K * 2; kb += 64) {   // kb = byte offset along K
    gload16(gA0 + kb, lA0);
    gload16(gA1 + kb, lA1);
    gload16(gB0 + kb, lB0);
    gload16(gB1 + kb, lB1);
    __syncthreads();            // compiler drains vmcnt(0): tile ready
    s16x8 af[4], bfr[4];
#pragma unroll
    for (int i = 0; i < 4; ++i) {
      af[i]  = *(const s16x8*)(As + (wm + i * 16 + fr) * 32 + fq * 8);
      bfr[i] = *(const s16x8*)(Bs + (wn + i * 16 + fr) * 32 + fq * 8);
    }
#pragma unroll
    for (int mi = 0; mi < 4; ++mi)
#pragma unroll
      for (int ni = 0; ni < 4; ++ni)
        acc[mi][ni] = __builtin_amdgcn_mfma_f32_16x16x32_bf16(af[mi], bfr[ni], acc[mi][ni], 0, 0, 0);
    __syncthreads();            // reads done: safe to overwrite next iter
  }

  // epilogue: C/D map col=lane&15, row=(lane>>4)*4+r
#pragma unroll
  for (int ni = 0; ni < 4; ++ni) {
    int col = bn0 + wn + ni * 16 + fr;
    float bb = bias[col];
#pragma unroll
    for (int mi = 0; mi < 4; ++mi)
#pragma unroll
      for (int r = 0; r < 4; ++r) {
        int row = bm0 + wm + mi * 16 + fq * 4 + r;
        if (row < M) {
          float v = acc[mi][ni][r] + bb;
          if (ACT) v = fmaxf(v, 0.f);
          if (OF32) ((float*)Cout)[(size_t)row * ldc + col] = v;
          else      ((unsigned short*)Cout)[(size_t)row * ldc + col] = f2bf(v);
        }
      }
  }
}

// ---------------- conversion / transpose kernels ----------------
__global__ void f32_to_bf16_k(const float* __restrict__ in, unsigned short* __restrict__ out, int n8) {
  int i = blockIdx.x * 256 + threadIdx.x;
  if (i >= n8) return;
  float4 a = ((const float4*)in)[2 * i];
  float4 b = ((const float4*)in)[2 * i + 1];
  uint4 p;
  p.x = pk2(a.x, a.y); p.y = pk2(a.z, a.w);
  p.z = pk2(b.x, b.y); p.w = pk2(b.z, b.w);
  ((uint4*)out)[i] = p;
}

// W[K,N] f32 -> Wt[N,K] bf16, 32x32 LDS tiles
__global__ void transpose_bf16_k(const float* __restrict__ W, unsigned short* __restrict__ Wt,
                                 int K, int N) {
  __shared__ float t[32][33];
  int n0 = blockIdx.x * 32, k0 = blockIdx.y * 32;
  int c = threadIdx.x & 31, r8 = threadIdx.x >> 5;
#pragma unroll
  for (int i = 0; i < 4; ++i) {
    int r = r8 + i * 8;
    t[r][c] = W[(size_t)(k0 + r) * N + n0 + c];
  }
  __syncthreads();
#pragma unroll
  for (int i = 0; i < 4; ++i) {
    int r = r8 + i * 8;
    Wt[(size_t)(n0 + r) * K + k0 + c] = f2bf(t[c][r]);
  }
}

// ---------------- misc ops ----------------
__global__ void softmax_p(const float* __restrict__ ps, float* __restrict__ score) {
  int b = blockIdx.x, lane = threadIdx.x;
  float v = (lane < P_) ? ps[b * P_ + lane] : -INFINITY;
  float m = v;
  for (int o = 32; o > 0; o >>= 1) m = fmaxf(m, __shfl_xor(m, o));
  float e = (lane < P_) ? __expf(v - m) : 0.f;
  float s = e;
  for (int o = 32; o > 0; o >>= 1) s += __shfl_xor(s, o);
  if (lane < P_) score[b * P_ + lane] = e / s;
}

#define TCH 128
// phase A: local in-place cumsum per (b, t-chunk, d)
__global__ void cumsum_local_k(float* __restrict__ v) {
  int d = blockIdx.x * 256 + threadIdx.x;
  int tc = blockIdx.y, b = blockIdx.z;
  float* p = v + ((size_t)b * T_ + tc * TCH) * D_ + d;
  float acc = 0.f;
  for (int t = 0; t < TCH; ++t) { acc += p[(size_t)t * D_]; p[(size_t)t * D_] = acc; }
}
// phase B: add prefix of chunk totals
__global__ void cumsum_fix_k(float* __restrict__ v) {
  int d = blockIdx.x * 256 + threadIdx.x;
  int tc = blockIdx.y + 1, b = blockIdx.z;
  const float* base = v + (size_t)b * T_ * D_ + d;
  float add = 0.f;
  for (int c = 0; c < tc; ++c) add += base[(size_t)(c * TCH + TCH - 1) * D_];
  float* p = v + ((size_t)b * T_ + tc * TCH) * D_ + d;
  for (int t = 0; t < TCH; ++t) p[(size_t)t * D_] += add;
}

__global__ void weighted_sum_para(const float* __restrict__ para_t, const float* __restrict__ score,
                                  float* __restrict__ out) {
  int d = blockIdx.x * 256 + threadIdx.x;
  int b = blockIdx.y;
  float acc = 0.f;
  for (int p = 0; p < P_; ++p)
    acc += score[b * P_ + p] * para_t[((size_t)b * P_ + p) * D_ + d];
  out[b * D_ + d] = acc;
}

__global__ void video_seg_k(const float* __restrict__ C, const float* __restrict__ score,
                            const int* __restrict__ starts, const int* __restrict__ ends,
                            float* __restrict__ out) {
  int d = blockIdx.x * 256 + threadIdx.x;
  int b = blockIdx.y;
  const float* Cb = C + (size_t)b * T_ * D_;
  float acc = 0.f;
  for (int p = 0; p < P_; ++p) {
    int s = starts[b * P_ + p], e = ends[b * P_ + p];
    float sc = score[b * P_ + p];
    float cs = (s > 0) ? Cb[(size_t)(s - 1) * D_ + d] : 0.f;
    float val;
    if (s >= e) val = Cb[(size_t)s * D_ + d] - cs;
    else        val = (Cb[(size_t)(e - 1) * D_ + d] - cs) / (float)(e - s);
    acc += sc * val;
  }
  out[b * D_ + d] = acc;
}

// fill inputs (bf16): cols [0:768)=vseg, [768:1536)=tseg, [1536:2304) += q
__global__ void build_inputs_k(unsigned short* __restrict__ inputs, const float* __restrict__ vseg,
                               const float* __restrict__ tseg, const float* __restrict__ q) {
  int idx = blockIdx.x * 256 + threadIdx.x;     // RA_*D_/8 threads
  int m = idx / 96, d8 = (idx % 96) * 8;
  int b = m / (S_ * A_);
  unsigned short* row = inputs + (size_t)m * D4_;
  float4 v0 = *(const float4*)(vseg + b * D_ + d8);
  float4 v1 = *(const float4*)(vseg + b * D_ + d8 + 4);
  uint4 pv; pv.x = pk2(v0.x, v0.y); pv.y = pk2(v0.z, v0.w); pv.z = pk2(v1.x, v1.y); pv.w = pk2(v1.z, v1.w);
  *(uint4*)(row + d8) = pv;
  float4 t0 = *(const float4*)(tseg + b * D_ + d8);
  float4 t1 = *(const float4*)(tseg + b * D_ + d8 + 4);
  uint4 pt; pt.x = pk2(t0.x, t0.y); pt.y = pk2(t0.z, t0.w); pt.z = pk2(t1.x, t1.y); pt.w = pk2(t1.z, t1.w);
  *(uint4*)(row + D_ + d8) = pt;
  s16x8 at = *(const s16x8*)(row + 2 * D_ + d8);
  float4 q0 = *(const float4*)(q + b * D_ + d8);
  float4 q1 = *(const float4*)(q + b * D_ + d8 + 4);
  float qa[8] = {q0.x, q0.y, q0.z, q0.w, q1.x, q1.y, q1.z, q1.w};
  s16x8 o;
#pragma unroll
  for (int j = 0; j < 8; ++j) o[j] = (short)f2bf(bf2f((unsigned short)at[j]) + qa[j]);
  *(s16x8*)(row + 2 * D_ + d8) = o;
}

// H[b,s] = s==0 ? state0 : x_all[b,s-1,label[b,s-1]]   (bf16)
__global__ void gather_h_k(const unsigned short* __restrict__ xall, const int* __restrict__ label,
                           const float* __restrict__ state0, unsigned short* __restrict__ H) {
  int idx = blockIdx.x * 256 + threadIdx.x;     // RH_*D_/8
  int m = idx / 96, d8 = (idx % 96) * 8;
  int b = m / S_, s = m % S_;
  if (s == 0) {
    float4 a = *(const float4*)(state0 + d8);
    float4 c = *(const float4*)(state0 + d8 + 4);
    uint4 p; p.x = pk2(a.x, a.y); p.y = pk2(a.z, a.w); p.z = pk2(c.x, c.y); p.w = pk2(c.z, c.w);
    *(uint4*)(H + (size_t)m * D_ + d8) = p;
  } else {
    int lab = label[b * S_ + (s - 1)];
    const unsigned short* src = xall + (((size_t)b * S_ + (s - 1)) * A_ + lab) * D_ + d8;
    *(uint4*)(H + (size_t)m * D_ + d8) = *(const uint4*)src;
  }
}

// GRU gates (bf16 in/out)
__global__ void gru_gates_k(const unsigned short* __restrict__ gi, const unsigned short* __restrict__ gh,
                            const unsigned short* __restrict__ H, unsigned short* __restrict__ hnew) {
  int idx = blockIdx.x * 256 + threadIdx.x;     // RA_*D_/8
  int m = idx / 96, d8 = (idx % 96) * 8;
  int bs = m / A_;
  const unsigned short* gim = gi + (size_t)m * G3_;
  const unsigned short* ghm = gh + (size_t)bs * G3_;
  s16x8 ir8 = *(const s16x8*)(gim + d8);
  s16x8 iz8 = *(const s16x8*)(gim + D_ + d8);
  s16x8 in8 = *(const s16x8*)(gim + 2 * D_ + d8);
  s16x8 hr8 = *(const s16x8*)(ghm + d8);
  s16x8 hz8 = *(const s16x8*)(ghm + D_ + d8);
  s16x8 hn8 = *(const s16x8*)(ghm + 2 * D_ + d8);
  s16x8 h8  = *(const s16x8*)(H + (size_t)bs * D_ + d8);
  s16x8 o;
#pragma unroll
  for (int j = 0; j < 8; ++j) {
    float r = 1.f / (1.f + __expf(-(bf2f((unsigned short)ir8[j]) + bf2f((unsigned short)hr8[j]))));
    float z = 1.f / (1.f + __expf(-(bf2f((unsigned short)iz8[j]) + bf2f((unsigned short)hz8[j]))));
    float n = tanhf(bf2f((unsigned short)in8[j]) + r * bf2f((unsigned short)hn8[j]));
    float h = bf2f((unsigned short)h8[j]);
    o[j] = (short)f2bf((1.f - z) * n + z * h);
  }
  *(s16x8*)(hnew + (size_t)m * D_ + d8) = o;
}

// logits[m] = dot(t1[m,:], wq2) + bq2
__global__ void logits_k(const unsigned short* __restrict__ t1, const float* __restrict__ wq2,
                         const float* __restrict__ bq2, float* __restrict__ logits) {
  int wid = threadIdx.x >> 6, lane = threadIdx.x & 63;
  int m = blockIdx.x * 4 + wid;
  const unsigned short* row = t1 + (size_t)m * D_;
  float acc = 0.f;
  for (int j = lane; j < D_; j += 64) acc += bf2f(row[j]) * wq2[j];
  for (int o = 32; o > 0; o >>= 1) acc += __shfl_xor(acc, o);
  if (lane == 0) logits[m] = acc + bq2[0];
}

__global__ void loss_k(const float* __restrict__ logits, const int* __restrict__ label,
                       float* __restrict__ out) {
  __shared__ float red[256];
  int tid = threadIdx.x;
  float ls = 0.f;
  if (tid < RH_) {
    const float* lg = logits + (size_t)tid * A_;
    float mx = -INFINITY;
    for (int a = 0; a < A_; ++a) mx = fmaxf(mx, lg[a]);
    float sum = 0.f;
    for (int a = 0; a < A_; ++a) sum += __expf(lg[a] - mx);
    ls = (logf(sum) + mx) - lg[label[tid]];
  }
  red[tid] = ls;
  for (int o = 128; o > 0; o >>= 1) {
    __syncthreads();
    if (tid < o) red[tid] += red[tid + o];
  }
  if (tid == 0) out[0] = red[0] / (float)RH_;
}

extern "C" void kernel_launch(void* const* d_in, const int* in_sizes, int n_in,
                              void* d_out, int out_size, void* d_ws, size_t ws_size,
                              hipStream_t stream) {
  (void)in_sizes; (void)n_in; (void)out_size; (void)ws_size;
  const float* video      = (const float*)d_in[0];
  const float* para       = (const float*)d_in[1];
  const float* question   = (const float*)d_in[2];
  const float* a_texts    = (const float*)d_in[3];
  const float* a_buttons  = (const float*)d_in[4];
  const float* paras_score= (const float*)d_in[5];
  const int*   starts     = (const int*)d_in[6];
  const int*   ends       = (const int*)d_in[7];
  const int*   label      = (const int*)d_in[8];
  const float* wv1 = (const float*)d_in[9];  const float* bv1 = (const float*)d_in[10];
  const float* wv2 = (const float*)d_in[11]; const float* bv2 = (const float*)d_in[12];
  const float* wt1 = (const float*)d_in[13]; const float* bt1 = (const float*)d_in[14];
  const float* wt2 = (const float*)d_in[15]; const float* bt2 = (const float*)d_in[16];
  const float* wp1 = (const float*)d_in[17]; const float* bp1 = (const float*)d_in[18];
  const float* wp2 = (const float*)d_in[19]; const float* bp2 = (const float*)d_in[20];
  const float* w_ih= (const float*)d_in[21]; const float* b_ih= (const float*)d_in[22];
  const float* w_hh= (const float*)d_in[23]; const float* b_hh= (const float*)d_in[24];
  const float* wq1 = (const float*)d_in[25]; const float* bq1 = (const float*)d_in[26];
  const float* wq2 = (const float*)d_in[27]; const float* bq2 = (const float*)d_in[28];
  const float* state0 = (const float*)d_in[29];

  char* base = (char*)d_ws;
  // byte offsets (total ~180.7 MB; round-0 used 182.7 MB successfully)
  unsigned short* wt1t = (unsigned short*)(base + 0);          // 768x768
  unsigned short* wt2t = (unsigned short*)(base + 1179648);
  unsigned short* wv1t = (unsigned short*)(base + 2359296);
  unsigned short* wv2t = (unsigned short*)(base + 3538944);
  unsigned short* wq1t = (unsigned short*)(base + 4718592);
  unsigned short* wp1t = (unsigned short*)(base + 5898240);    // 3072x3072
  unsigned short* wp2t = (unsigned short*)(base + 24772608);   // 768x3072 (Wt layout [N,K])
  unsigned short* wiht = (unsigned short*)(base + 29491200);   // 2304x768
  unsigned short* whht = (unsigned short*)(base + 33030144);   // 2304x768
  unsigned short* Vr   = (unsigned short*)(base + 36569088);   // 25.2MB: video_bf / at_bf / ab_bf / hnew
  unsigned short* Hr   = (unsigned short*)(base + 61734912);   // 28.3MB: MLP hiddens / hidden_p / t1
  unsigned short* Ir   = (unsigned short*)(base + 90046464);   // 28.3MB: inputs [4608,3072]
  float*          Fr   = (float*)         (base + 118358016);  // 50.3MB: video_v f32; later gi bf16
  unsigned short* xall = (unsigned short*)(base + 168689664);  // 7.1MB
  unsigned short* parab= (unsigned short*)(base + 175767552);  // para bf16
  unsigned short* qsb  = (unsigned short*)(base + 176947200);  // question bf16
  float* para_t = (float*)(base + 176971776);
  float* score  = (float*)(base + 179331072);
  float* tseg   = (float*)(base + 179334144);
  float* vseg   = (float*)(base + 179383296);
  unsigned short* qh = (unsigned short*)(base + 179432448);
  float* qv     = (float*)(base + 179457024);
  unsigned short* Hbf = (unsigned short*)(base + 179506176);   // [192,768]
  unsigned short* ghb = (unsigned short*)(base + 179801088);   // [192,2304]
  float* logits = (float*)(base + 180685824);
  unsigned short* gib = (unsigned short*)Fr;                   // gi bf16 reuses Fr
  unsigned short* hnew = Vr;
  unsigned short* t1 = Hr;

  dim3 blk(256);

  // ---- weight transpose+convert (Wt[N,K] bf16) ----
  transpose_bf16_k<<<dim3(24, 24), blk, 0, stream>>>(wt1, wt1t, D_, D_);
  transpose_bf16_k<<<dim3(24, 24), blk, 0, stream>>>(wt2, wt2t, D_, D_);
  transpose_bf16_k<<<dim3(24, 24), blk, 0, stream>>>(wv1, wv1t, D_, D_);
  transpose_bf16_k<<<dim3(24, 24), blk, 0, stream>>>(wv2, wv2t, D_, D_);
  transpose_bf16_k<<<dim3(24, 24), blk, 0, stream>>>(wq1, wq1t, D_, D_);
  transpose_bf16_k<<<dim3(96, 96), blk, 0, stream>>>(wp1, wp1t, D4_, D4_);
  transpose_bf16_k<<<dim3(24, 96), blk, 0, stream>>>(wp2, wp2t, D4_, D_);
  transpose_bf16_k<<<dim3(72, 24), blk, 0, stream>>>(w_ih, wiht, D_, G3_);
  transpose_bf16_k<<<dim3(72, 24), blk, 0, stream>>>(w_hh, whht, D_, G3_);

  // ---- small front ----
  softmax_p<<<B_, 64, 0, stream>>>(paras_score, score);
  f32_to_bf16_k<<<288, blk, 0, stream>>>(para, parab, RP_ * D_ / 8);
  f32_to_bf16_k<<<6, blk, 0, stream>>>(question, qsb, B_ * D_ / 8);

  // para MLP -> para_t (f32)
  gemm_bf16<1,0><<<dim3(6, 6), blk, 0, stream>>>(parab, wt1t, bt1, Hr, D_, RP_, D_, D_);
  gemm_bf16<0,1><<<dim3(6, 6), blk, 0, stream>>>(Hr, wt2t, bt2, para_t, D_, RP_, D_, D_);
  weighted_sum_para<<<dim3(3, B_), blk, 0, stream>>>(para_t, score, tseg);

  // video MLP -> vv f32, cumsum, video_seg
  f32_to_bf16_k<<<6144, blk, 0, stream>>>(video, Vr, RV_ * D_ / 8);
  gemm_bf16<1,0><<<dim3(6, 128), blk, 0, stream>>>(Vr, wv1t, bv1, Hr, D_, RV_, D_, D_);
  gemm_bf16<0,1><<<dim3(6, 128), blk, 0, stream>>>(Hr, wv2t, bv2, Fr, D_, RV_, D_, D_);
  cumsum_local_k<<<dim3(3, 8, B_), blk, 0, stream>>>(Fr);
  cumsum_fix_k<<<dim3(3, 7, B_), blk, 0, stream>>>(Fr);
  video_seg_k<<<dim3(3, B_), blk, 0, stream>>>(Fr, score, starts, ends, vseg);

  // q MLP -> qv f32
  gemm_bf16<1,0><<<dim3(6, 1), blk, 0, stream>>>(qsb, wt1t, bt1, qh, D_, B_, D_, D_);
  gemm_bf16<0,1><<<dim3(6, 1), blk, 0, stream>>>(qh, wt2t, bt2, qv, D_, B_, D_, D_);

  // at MLP -> inputs cols [1536:2304)
  f32_to_bf16_k<<<4608, blk, 0, stream>>>(a_texts, Vr, RA_ * D_ / 8);
  gemm_bf16<1,0><<<dim3(6, 36), blk, 0, stream>>>(Vr, wt1t, bt1, Hr, D_, RA_, D_, D_);
  gemm_bf16<0,0><<<dim3(6, 36), blk, 0, stream>>>(Hr, wt2t, bt2, Ir + 2 * D_, D4_, RA_, D_, D_);
  // ab MLP -> inputs cols [2304:3072)
  f32_to_bf16_k<<<4608, blk, 0, stream>>>(a_buttons, Vr, RA_ * D_ / 8);
  gemm_bf16<1,0><<<dim3(6, 36), blk, 0, stream>>>(Vr, wv1t, bv1, Hr, D_, RA_, D_, D_);
  gemm_bf16<0,0><<<dim3(6, 36), blk, 0, stream>>>(Hr, wv2t, bv2, Ir + 3 * D_, D4_, RA_, D_, D_);
  // broadcast seg cols + q add
  build_inputs_k<<<RA_ * D_ / 8 / 256, blk, 0, stream>>>(Ir, vseg, tseg, qv);

  // predictor MLP
  gemm_bf16<1,0><<<dim3(24, 36), blk, 0, stream>>>(Ir, wp1t, bp1, Hr, D4_, RA_, D4_, D4_);
  gemm_bf16<0,0><<<dim3(6, 36), blk, 0, stream>>>(Hr, wp2t, bp2, xall, D_, RA_, D_, D4_);

  // GRU (parallel over s: h comes from x_all/labels)
  gather_h_k<<<RH_ * D_ / 8 / 256, blk, 0, stream>>>(xall, label, state0, Hbf);
  gemm_bf16<0,0><<<dim3(18, 36), blk, 0, stream>>>(xall, wiht, b_ih, gib, G3_, RA_, G3_, D_);
  gemm_bf16<0,0><<<dim3(18, 2), blk, 0, stream>>>(Hbf, whht, b_hh, ghb, G3_, RH_, G3_, D_);
  gru_gates_k<<<RA_ * D_ / 8 / 256, blk, 0, stream>>>(gib, ghb, Hbf, hnew);
  gemm_bf16<1,0><<<dim3(6, 36), blk, 0, stream>>>(hnew, wq1t, bq1, t1, D_, RA_, D_, D_);
  logits_k<<<RA_ / 4, blk, 0, stream>>>(t1, wq2, bq2, logits);
  loss_k<<<1, blk, 0, stream>>>(logits, label, (float*)d_out);
}

// Round 3
// 783.191 us; speedup vs baseline: 1.6055x; 1.2415x over previous
//
#include <hip/hip_runtime.h>
#include <hip/hip_bf16.h>
#include <math.h>

#define B_ 16
#define T_ 1024
#define P_ 48
#define S_ 12
#define A_ 24
#define D_ 768
#define D4_ 3072
#define G3_ 2304
#define RV_ (B_*T_)      // 16384
#define RP_ (B_*P_)      // 768
#define RA_ (B_*S_*A_)   // 4608
#define RH_ (B_*S_)      // 192
#define RPB_ 288         // rows per batch in RA_ (S_*A_)

typedef float f32x4 __attribute__((ext_vector_type(4)));
typedef short s16x8 __attribute__((ext_vector_type(8)));

__device__ __forceinline__ unsigned short f2bf(float f) {
  unsigned int u = __float_as_uint(f);
  u += 0x7FFF + ((u >> 16) & 1);   // RNE
  return (unsigned short)(u >> 16);
}
__device__ __forceinline__ unsigned int pk2(float lo, float hi) {
  return (unsigned int)f2bf(lo) | ((unsigned int)f2bf(hi) << 16);
}
__device__ __forceinline__ float bf2f(unsigned short u) {
  return __uint_as_float(((unsigned int)u) << 16);
}
__device__ __forceinline__ void gload16(const void* g, void* l) {
  __builtin_amdgcn_global_load_lds((const __attribute__((address_space(1))) void*)g,
                                   (__attribute__((address_space(3))) void*)l, 16, 0, 0);
}
// bijective XCD swizzle (m204): consecutive swizzled ids land on same XCD
__device__ __forceinline__ int xcd_swizzle(int orig, int nwg) {
  int q = nwg >> 3, r = nwg & 7;
  int xcd = orig & 7, local = orig >> 3;
  return (xcd < r ? xcd * (q + 1) : r * (q + 1) + (xcd - r) * q) + local;
}

// ---------------- gemm128: 128x128 tile, BK=32, 4 waves (m97 structure) ----------------
// C = act(A[M,K] @ Wt[N,K]^T + bias). K%32==0, N%128==0, M arbitrary.
// B2D: bias is [B_][N] indexed by row/RPB_ (f32), else 1D [N].
template<int ACT, int OF32, int B2D>
__global__ __launch_bounds__(256)
void gemm128(const unsigned short* __restrict__ A,
             const unsigned short* __restrict__ Wt,
             const float* __restrict__ bias,
             void* __restrict__ Cout, int ldc,
             int M, int N, int K)
{
  __shared__ __align__(16) unsigned short As[4096];   // [128][32]
  __shared__ __align__(16) unsigned short Bs[4096];
  const int tid  = threadIdx.x;
  const int lane = tid & 63;
  const int wid  = tid >> 6;
  const int wm = (wid >> 1) * 64, wn = (wid & 1) * 64;
  const int gx = gridDim.x;
  int swz = xcd_swizzle(blockIdx.y * gx + blockIdx.x, gx * gridDim.y);
  const int bm0 = (swz / gx) * 128, bn0 = (swz % gx) * 128;

  int arow = wid * 16 + (lane >> 2);
  int ar0 = bm0 + arow;       if (ar0 > M - 1) ar0 = M - 1;
  int ar1 = bm0 + arow + 64;  if (ar1 > M - 1) ar1 = M - 1;
  const char* gA0 = (const char*)(A + (size_t)ar0 * K) + (lane & 3) * 16;
  const char* gA1 = (const char*)(A + (size_t)ar1 * K) + (lane & 3) * 16;
  const char* gB0 = (const char*)(Wt + (size_t)(bn0 + arow) * K) + (lane & 3) * 16;
  const char* gB1 = (const char*)(Wt + (size_t)(bn0 + arow + 64) * K) + (lane & 3) * 16;
  unsigned short* lA0 = As + wid * 512;
  unsigned short* lA1 = As + 2048 + wid * 512;
  unsigned short* lB0 = Bs + wid * 512;
  unsigned short* lB1 = Bs + 2048 + wid * 512;

  f32x4 acc[4][4] = {};
  const int fr = lane & 15, fq = lane >> 4;

  for (int kb = 0; kb < K * 2; kb += 64) {
    gload16(gA0 + kb, lA0);
    gload16(gA1 + kb, lA1);
    gload16(gB0 + kb, lB0);
    gload16(gB1 + kb, lB1);
    __syncthreads();
    s16x8 af[4], bfr[4];
#pragma unroll
    for (int i = 0; i < 4; ++i) {
      af[i]  = *(const s16x8*)(As + (wm + i * 16 + fr) * 32 + fq * 8);
      bfr[i] = *(const s16x8*)(Bs + (wn + i * 16 + fr) * 32 + fq * 8);
    }
#pragma unroll
    for (int mi = 0; mi < 4; ++mi)
#pragma unroll
      for (int ni = 0; ni < 4; ++ni)
        acc[mi][ni] = __builtin_amdgcn_mfma_f32_16x16x32_bf16(af[mi], bfr[ni], acc[mi][ni], 0, 0, 0);
    __syncthreads();
  }

#pragma unroll
  for (int ni = 0; ni < 4; ++ni) {
    int col = bn0 + wn + ni * 16 + fr;
    float bb = B2D ? 0.f : bias[col];
#pragma unroll
    for (int mi = 0; mi < 4; ++mi)
#pragma unroll
      for (int r = 0; r < 4; ++r) {
        int row = bm0 + wm + mi * 16 + fq * 4 + r;
        if (row < M) {
          float v = acc[mi][ni][r] + (B2D ? bias[(size_t)(row / RPB_) * N + col] : bb);
          if (ACT) v = fmaxf(v, 0.f);
          if (OF32) ((float*)Cout)[(size_t)row * ldc + col] = v;
          else      ((unsigned short*)Cout)[(size_t)row * ldc + col] = f2bf(v);
        }
      }
  }
}

// ---------------- gemm256: 256x256 tile, BK=64, 8 waves, 2-phase double-buffered ----------
// Requires M%256==0, N%256==0, K%64==0.
template<int ACT, int OF32, int B2D>
__global__ __launch_bounds__(512, 2)
void gemm256(const unsigned short* __restrict__ A,
             const unsigned short* __restrict__ Wt,
             const float* __restrict__ bias,
             void* __restrict__ Cout, int ldc,
             int M, int N, int K)
{
  __shared__ __align__(16) unsigned short As[2][16384];  // [buf][256 rows][64 k]
  __shared__ __align__(16) unsigned short Bs[2][16384];
  const int tid  = threadIdx.x;
  const int lane = tid & 63;
  const int wid  = tid >> 6;                 // 0..7
  const int wm = (wid >> 2) * 128;           // 2 waves along M
  const int wn = (wid & 3) * 64;             // 4 waves along N
  const int gx = gridDim.x;
  int swz = xcd_swizzle(blockIdx.y * gx + blockIdx.x, gx * gridDim.y);
  const int bm0 = (swz / gx) * 256, bn0 = (swz % gx) * 256;

  // staging: wave wid, chunk c (0..3) covers rows wid*32 + c*8 + (lane>>3), kseg (lane&7)*8
  const int srow = wid * 32 + (lane >> 3);
  const int skseg = (lane & 7) * 8;
  const unsigned short* gA = A  + (size_t)(bm0 + srow) * K + skseg;
  const unsigned short* gB = Wt + (size_t)(bn0 + srow) * K + skseg;

  f32x4 acc[8][4] = {};
  const int fr = lane & 15, fq = lane >> 4;
  const int nt = K / 64;

  // prologue: stage buf 0, tile 0
#pragma unroll
  for (int c = 0; c < 4; ++c) {
    gload16(gA + (size_t)c * 8 * K, &As[0][wid * 2048 + c * 512]);
    gload16(gB + (size_t)c * 8 * K, &Bs[0][wid * 2048 + c * 512]);
  }
  __syncthreads();

  for (int t = 0; t < nt; ++t) {
    if (t + 1 < nt) {
      int nb = (t + 1) & 1;
      size_t ko = (size_t)(t + 1) * 64;
#pragma unroll
      for (int c = 0; c < 4; ++c) {
        gload16(gA + (size_t)c * 8 * K + ko, &As[nb][wid * 2048 + c * 512]);
        gload16(gB + (size_t)c * 8 * K + ko, &Bs[nb][wid * 2048 + c * 512]);
      }
    }
    const int cb = t & 1;
#pragma unroll
    for (int ks = 0; ks < 2; ++ks) {
      s16x8 af[8], bfr[4];
#pragma unroll
      for (int i = 0; i < 8; ++i)
        af[i] = *(const s16x8*)(&As[cb][(wm + i * 16 + fr) * 64 + ks * 32 + fq * 8]);
#pragma unroll
      for (int i = 0; i < 4; ++i)
        bfr[i] = *(const s16x8*)(&Bs[cb][(wn + i * 16 + fr) * 64 + ks * 32 + fq * 8]);
#pragma unroll
      for (int mi = 0; mi < 8; ++mi)
#pragma unroll
        for (int ni = 0; ni < 4; ++ni)
          acc[mi][ni] = __builtin_amdgcn_mfma_f32_16x16x32_bf16(af[mi], bfr[ni], acc[mi][ni], 0, 0, 0);
    }
    __syncthreads();   // drains vmcnt (next buf staged) + all reads of cur buf done
  }

#pragma unroll
  for (int ni = 0; ni < 4; ++ni) {
    int col = bn0 + wn + ni * 16 + fr;
    float bb = B2D ? 0.f : bias[col];
#pragma unroll
    for (int mi = 0; mi < 8; ++mi)
#pragma unroll
      for (int r = 0; r < 4; ++r) {
        int row = bm0 + wm + mi * 16 + fq * 4 + r;
        float v = acc[mi][ni][r] + (B2D ? bias[(size_t)(row / RPB_) * N + col] : bb);
        if (ACT) v = fmaxf(v, 0.f);
        if (OF32) ((float*)Cout)[(size_t)row * ldc + col] = v;
        else      ((unsigned short*)Cout)[(size_t)row * ldc + col] = f2bf(v);
      }
  }
}

// ---------------- conversion / transpose ----------------
// one kernel packs all five f32 inputs to bf16 concat buffers
__global__ void pack_bf16_k(const float* __restrict__ video, const float* __restrict__ abut,
                            const float* __restrict__ para, const float* __restrict__ atex,
                            const float* __restrict__ quest,
                            unsigned short* __restrict__ Vcat, unsigned short* __restrict__ Tcat) {
  int idx = blockIdx.x * 256 + threadIdx.x;
  int r = idx / 96, d8 = (idx % 96) * 8;
  const float* src; unsigned short* dst;
  if (r < 16384)      { src = video + (size_t)r * D_;           dst = Vcat + (size_t)r * D_; }
  else if (r < 20992) { src = abut + (size_t)(r - 16384) * D_;  dst = Vcat + (size_t)r * D_; }
  else if (r < 21760) { src = para + (size_t)(r - 20992) * D_;  dst = Tcat + (size_t)(r - 20992) * D_; }
  else if (r < 26368) { src = atex + (size_t)(r - 21760) * D_;  dst = Tcat + (size_t)(r - 20992) * D_; }
  else                { src = quest + (size_t)(r - 26368) * D_; dst = Tcat + (size_t)(r - 20992) * D_; }
  float4 a = *(const float4*)(src + d8);
  float4 b = *(const float4*)(src + d8 + 4);
  uint4 p; p.x = pk2(a.x, a.y); p.y = pk2(a.z, a.w); p.z = pk2(b.x, b.y); p.w = pk2(b.z, b.w);
  *(uint4*)(dst + d8) = p;
}

// W[K,N] f32 -> Wt[N,K] bf16
__global__ void transpose_bf16_k(const float* __restrict__ W, unsigned short* __restrict__ Wt,
                                 int K, int N) {
  __shared__ float t[32][33];
  int n0 = blockIdx.x * 32, k0 = blockIdx.y * 32;
  int c = threadIdx.x & 31, r8 = threadIdx.x >> 5;
#pragma unroll
  for (int i = 0; i < 4; ++i) {
    int r = r8 + i * 8;
    t[r][c] = W[(size_t)(k0 + r) * N + n0 + c];
  }
  __syncthreads();
#pragma unroll
  for (int i = 0; i < 4; ++i) {
    int r = r8 + i * 8;
    Wt[(size_t)(n0 + r) * K + k0 + c] = f2bf(t[c][r]);
  }
}

// ---------------- misc ----------------
__global__ void softmax_p(const float* __restrict__ ps, float* __restrict__ score) {
  int b = blockIdx.x, lane = threadIdx.x;
  float v = (lane < P_) ? ps[b * P_ + lane] : -INFINITY;
  float m = v;
  for (int o = 32; o > 0; o >>= 1) m = fmaxf(m, __shfl_xor(m, o));
  float e = (lane < P_) ? __expf(v - m) : 0.f;
  float s = e;
  for (int o = 32; o > 0; o >>= 1) s += __shfl_xor(s, o);
  if (lane < P_) score[b * P_ + lane] = e / s;
}

#define TCH 128
__global__ void cumsum_local_k(float* __restrict__ v) {
  int d = blockIdx.x * 256 + threadIdx.x;
  int tc = blockIdx.y, b = blockIdx.z;
  float* p = v + ((size_t)b * T_ + tc * TCH) * D_ + d;
  float acc = 0.f;
  for (int t = 0; t < TCH; ++t) { acc += p[(size_t)t * D_]; p[(size_t)t * D_] = acc; }
}
__global__ void cumsum_fix_k(float* __restrict__ v) {
  int d = blockIdx.x * 256 + threadIdx.x;
  int tc = blockIdx.y + 1, b = blockIdx.z;
  const float* base = v + (size_t)b * T_ * D_ + d;
  float add = 0.f;
  for (int c = 0; c < tc; ++c) add += base[(size_t)(c * TCH + TCH - 1) * D_];
  float* p = v + ((size_t)b * T_ + tc * TCH) * D_ + d;
  for (int t = 0; t < TCH; ++t) p[(size_t)t * D_] += add;
}

__global__ void weighted_sum_para(const float* __restrict__ para_t, const float* __restrict__ score,
                                  float* __restrict__ out) {
  int d = blockIdx.x * 256 + threadIdx.x;
  int b = blockIdx.y;
  float acc = 0.f;
  for (int p = 0; p < P_; ++p)
    acc += score[b * P_ + p] * para_t[((size_t)b * P_ + p) * D_ + d];
  out[b * D_ + d] = acc;
}

__global__ void video_seg_k(const float* __restrict__ C, const float* __restrict__ score,
                            const int* __restrict__ starts, const int* __restrict__ ends,
                            float* __restrict__ out) {
  int d = blockIdx.x * 256 + threadIdx.x;
  int b = blockIdx.y;
  const float* Cb = C + (size_t)b * T_ * D_;
  float acc = 0.f;
  for (int p = 0; p < P_; ++p) {
    int s = starts[b * P_ + p], e = ends[b * P_ + p];
    float sc = score[b * P_ + p];
    float cs = (s > 0) ? Cb[(size_t)(s - 1) * D_ + d] : 0.f;
    float val;
    if (s >= e) val = Cb[(size_t)s * D_ + d] - cs;
    else        val = (Cb[(size_t)(e - 1) * D_ + d] - cs) / (float)(e - s);
    acc += sc * val;
  }
  out[b * D_ + d] = acc;
}

// QAB cols [0:768) = bf16(at + q)   (at rows = Tout[768+m], q = Tout[5376+b])
__global__ void build_qa_k(const float* __restrict__ Tout, unsigned short* __restrict__ QAB) {
  int idx = blockIdx.x * 256 + threadIdx.x;     // RA_*96
  int m = idx / 96, d8 = (idx % 96) * 8;
  int b = m / RPB_;
  const float* at = Tout + (size_t)(RP_ + m) * D_ + d8;
  const float* qq = Tout + (size_t)(RP_ + RA_ + b) * D_ + d8;
  unsigned short* dst = QAB + (size_t)m * 1536 + d8;
  uint4 p;
  p.x = pk2(at[0] + qq[0], at[1] + qq[1]);
  p.y = pk2(at[2] + qq[2], at[3] + qq[3]);
  p.z = pk2(at[4] + qq[4], at[5] + qq[5]);
  p.w = pk2(at[6] + qq[6], at[7] + qq[7]);
  *(uint4*)dst = p;
}

// A2[b] = bf16(vseg[b] ‖ tseg[b])   [16,1536]
__global__ void seg2bf_k(const float* __restrict__ vseg, const float* __restrict__ tseg,
                         unsigned short* __restrict__ A2) {
  int idx = blockIdx.x * 256 + threadIdx.x;   // 16*192
  int b = idx / 192, seg = (idx % 192) * 8;
  const float* src = (seg < D_) ? (vseg + b * D_ + seg) : (tseg + b * D_ + seg - D_);
  float4 a = *(const float4*)src;
  float4 c = *(const float4*)(src + 4);
  uint4 p; p.x = pk2(a.x, a.y); p.y = pk2(a.z, a.w); p.z = pk2(c.x, c.y); p.w = pk2(c.z, c.w);
  *(uint4*)(A2 + (size_t)b * 1536 + seg) = p;
}

__global__ void gather_h_k(const unsigned short* __restrict__ xall, const int* __restrict__ label,
                           const float* __restrict__ state0, unsigned short* __restrict__ H) {
  int idx = blockIdx.x * 256 + threadIdx.x;     // RH_*96
  int m = idx / 96, d8 = (idx % 96) * 8;
  int b = m / S_, s = m % S_;
  if (s == 0) {
    float4 a = *(const float4*)(state0 + d8);
    float4 c = *(const float4*)(state0 + d8 + 4);
    uint4 p; p.x = pk2(a.x, a.y); p.y = pk2(a.z, a.w); p.z = pk2(c.x, c.y); p.w = pk2(c.z, c.w);
    *(uint4*)(H + (size_t)m * D_ + d8) = p;
  } else {
    int lab = label[b * S_ + (s - 1)];
    const unsigned short* src = xall + (((size_t)b * S_ + (s - 1)) * A_ + lab) * D_ + d8;
    *(uint4*)(H + (size_t)m * D_ + d8) = *(const uint4*)src;
  }
}

__global__ void gru_gates_k(const unsigned short* __restrict__ gi, const unsigned short* __restrict__ gh,
                            const unsigned short* __restrict__ H, unsigned short* __restrict__ hnew) {
  int idx = blockIdx.x * 256 + threadIdx.x;     // RA_*96
  int m = idx / 96, d8 = (idx % 96) * 8;
  int bs = m / A_;
  const unsigned short* gim = gi + (size_t)m * G3_;
  const unsigned short* ghm = gh + (size_t)bs * G3_;
  s16x8 ir8 = *(const s16x8*)(gim + d8);
  s16x8 iz8 = *(const s16x8*)(gim + D_ + d8);
  s16x8 in8 = *(const s16x8*)(gim + 2 * D_ + d8);
  s16x8 hr8 = *(const s16x8*)(ghm + d8);
  s16x8 hz8 = *(const s16x8*)(ghm + D_ + d8);
  s16x8 hn8 = *(const s16x8*)(ghm + 2 * D_ + d8);
  s16x8 h8  = *(const s16x8*)(H + (size_t)bs * D_ + d8);
  s16x8 o;
#pragma unroll
  for (int j = 0; j < 8; ++j) {
    float r = 1.f / (1.f + __expf(-(bf2f((unsigned short)ir8[j]) + bf2f((unsigned short)hr8[j]))));
    float z = 1.f / (1.f + __expf(-(bf2f((unsigned short)iz8[j]) + bf2f((unsigned short)hz8[j]))));
    float n = tanhf(bf2f((unsigned short)in8[j]) + r * bf2f((unsigned short)hn8[j]));
    float h = bf2f((unsigned short)h8[j]);
    o[j] = (short)f2bf((1.f - z) * n + z * h);
  }
  *(s16x8*)(hnew + (size_t)m * D_ + d8) = o;
}

__global__ void logits_k(const unsigned short* __restrict__ t1, const float* __restrict__ wq2,
                         const float* __restrict__ bq2, float* __restrict__ logits) {
  int wid = threadIdx.x >> 6, lane = threadIdx.x & 63;
  int m = blockIdx.x * 4 + wid;
  const unsigned short* row = t1 + (size_t)m * D_;
  float acc = 0.f;
  for (int j = lane; j < D_; j += 64) acc += bf2f(row[j]) * wq2[j];
  for (int o = 32; o > 0; o >>= 1) acc += __shfl_xor(acc, o);
  if (lane == 0) logits[m] = acc + bq2[0];
}

__global__ void loss_k(const float* __restrict__ logits, const int* __restrict__ label,
                       float* __restrict__ out) {
  __shared__ float red[256];
  int tid = threadIdx.x;
  float ls = 0.f;
  if (tid < RH_) {
    const float* lg = logits + (size_t)tid * A_;
    float mx = -INFINITY;
    for (int a = 0; a < A_; ++a) mx = fmaxf(mx, lg[a]);
    float sum = 0.f;
    for (int a = 0; a < A_; ++a) sum += __expf(lg[a] - mx);
    ls = (logf(sum) + mx) - lg[label[tid]];
  }
  red[tid] = ls;
  for (int o = 128; o > 0; o >>= 1) {
    __syncthreads();
    if (tid < o) red[tid] += red[tid + o];
  }
  if (tid == 0) out[0] = red[0] / (float)RH_;
}

extern "C" void kernel_launch(void* const* d_in, const int* in_sizes, int n_in,
                              void* d_out, int out_size, void* d_ws, size_t ws_size,
                              hipStream_t stream) {
  (void)in_sizes; (void)n_in; (void)out_size; (void)ws_size;
  const float* video      = (const float*)d_in[0];
  const float* para       = (const float*)d_in[1];
  const float* question   = (const float*)d_in[2];
  const float* a_texts    = (const float*)d_in[3];
  const float* a_buttons  = (const float*)d_in[4];
  const float* paras_score= (const float*)d_in[5];
  const int*   starts     = (const int*)d_in[6];
  const int*   ends       = (const int*)d_in[7];
  const int*   label      = (const int*)d_in[8];
  const float* wv1 = (const float*)d_in[9];  const float* bv1 = (const float*)d_in[10];
  const float* wv2 = (const float*)d_in[11]; const float* bv2 = (const float*)d_in[12];
  const float* wt1 = (const float*)d_in[13]; const float* bt1 = (const float*)d_in[14];
  const float* wt2 = (const float*)d_in[15]; const float* bt2 = (const float*)d_in[16];
  const float* wp1 = (const float*)d_in[17]; const float* bp1 = (const float*)d_in[18];
  const float* wp2 = (const float*)d_in[19]; const float* bp2 = (const float*)d_in[20];
  const float* w_ih= (const float*)d_in[21]; const float* b_ih= (const float*)d_in[22];
  const float* w_hh= (const float*)d_in[23]; const float* b_hh= (const float*)d_in[24];
  const float* wq1 = (const float*)d_in[25]; const float* bq1 = (const float*)d_in[26];
  const float* wq2 = (const float*)d_in[27]; const float* bq2 = (const float*)d_in[28];
  const float* state0 = (const float*)d_in[29];

  char* base = (char*)d_ws;
  unsigned short* wt1t = (unsigned short*)(base + 0);
  unsigned short* wt2t = (unsigned short*)(base + 1179648);
  unsigned short* wv1t = (unsigned short*)(base + 2359296);
  unsigned short* wv2t = (unsigned short*)(base + 3538944);
  unsigned short* wq1t = (unsigned short*)(base + 4718592);
  unsigned short* wp1tt= (unsigned short*)(base + 5898240);   // [3072,1536] top
  unsigned short* wp1bt= (unsigned short*)(base + 15335424);  // [3072,1536] bottom
  unsigned short* wp2t = (unsigned short*)(base + 24772608);  // [768,3072]
  unsigned short* wiht = (unsigned short*)(base + 29491200);  // [2304,768]
  unsigned short* whht = (unsigned short*)(base + 33030144);
  // R1: Vcat bf16 (32.2MB) -> Fout f32 video (50.3MB) -> hidden_p bf16 (28.3MB)
  char* R1 = base + 36569088;
  unsigned short* Vcat = (unsigned short*)R1;
  float*          Fout = (float*)R1;
  unsigned short* hidp = (unsigned short*)R1;
  // R2: Thid/Vhid bf16 (32.2MB) -> gib bf16 (21.2MB)
  char* R2 = base + 86900736;
  unsigned short* Hid = (unsigned short*)R2;
  unsigned short* gib = (unsigned short*)R2;
  unsigned short* Tcat = (unsigned short*)(base + 119144448); // 8.3MB
  // R4: Tout f32 (16.6MB) -> t1 bf16 (7.1MB)
  char* R4 = base + 127426560;
  float* Tout = (float*)R4;
  unsigned short* t1 = (unsigned short*)R4;
  // R5: QAB bf16 (14.2MB) -> hnew bf16 (7.1MB)
  char* R5 = base + 143990784;
  unsigned short* QAB = (unsigned short*)R5;
  unsigned short* hnew = (unsigned short*)R5;
  unsigned short* xall = (unsigned short*)(base + 158146560); // 7.1MB
  float* score  = (float*)(base + 165224448);
  float* tseg   = (float*)(base + 165227520);
  float* vseg   = (float*)(base + 165276672);
  unsigned short* A2 = (unsigned short*)(base + 165325824);
  float* baseb  = (float*)(base + 165374976);                 // [16,3072]
  unsigned short* Hbf = (unsigned short*)(base + 165571584);  // [192,768]
  unsigned short* ghb = (unsigned short*)(base + 165866496);  // [192,2304]
  float* logits = (float*)(base + 166751232);

  dim3 blk(256), blk5(512);

  // weights: transpose + bf16
  transpose_bf16_k<<<dim3(24, 24), blk, 0, stream>>>(wt1, wt1t, D_, D_);
  transpose_bf16_k<<<dim3(24, 24), blk, 0, stream>>>(wt2, wt2t, D_, D_);
  transpose_bf16_k<<<dim3(24, 24), blk, 0, stream>>>(wv1, wv1t, D_, D_);
  transpose_bf16_k<<<dim3(24, 24), blk, 0, stream>>>(wv2, wv2t, D_, D_);
  transpose_bf16_k<<<dim3(24, 24), blk, 0, stream>>>(wq1, wq1t, D_, D_);
  transpose_bf16_k<<<dim3(96, 48), blk, 0, stream>>>(wp1, wp1tt, 1536, D4_);
  transpose_bf16_k<<<dim3(96, 48), blk, 0, stream>>>(wp1 + 1536 * D4_, wp1bt, 1536, D4_);
  transpose_bf16_k<<<dim3(24, 96), blk, 0, stream>>>(wp2, wp2t, D4_, D_);
  transpose_bf16_k<<<dim3(72, 24), blk, 0, stream>>>(w_ih, wiht, D_, G3_);
  transpose_bf16_k<<<dim3(72, 24), blk, 0, stream>>>(w_hh, whht, D_, G3_);

  softmax_p<<<B_, 64, 0, stream>>>(paras_score, score);
  pack_bf16_k<<<9894, blk, 0, stream>>>(video, a_buttons, para, a_texts, question, Vcat, Tcat);

  // MLP_t chain over [para; a_texts; question] = 5392 rows
  gemm128<1,0,0><<<dim3(6, 43), blk, 0, stream>>>(Tcat, wt1t, bt1, Hid, D_, 5392, D_, D_);
  gemm128<0,1,0><<<dim3(6, 43), blk, 0, stream>>>(Hid, wt2t, bt2, Tout, D_, 5392, D_, D_);
  weighted_sum_para<<<dim3(3, B_), blk, 0, stream>>>(Tout, score, tseg);

  // MLP_v chain over [video; a_buttons] = 20992 rows
  gemm256<1,0,0><<<dim3(3, 82), blk5, 0, stream>>>(Vcat, wv1t, bv1, Hid, D_, 20992, D_, D_);
  gemm256<0,1,0><<<dim3(3, 64), blk5, 0, stream>>>(Hid, wv2t, bv2, Fout, D_, RV_, D_, D_);          // video rows -> f32
  gemm128<0,0,0><<<dim3(6, 36), blk, 0, stream>>>(Hid + (size_t)RV_ * D_, wv2t, bv2,
                                                  QAB + D_, 1536, RA_, D_, D_);                     // ab rows -> QAB[:,768:)
  cumsum_local_k<<<dim3(3, 8, B_), blk, 0, stream>>>(Fout);
  cumsum_fix_k<<<dim3(3, 7, B_), blk, 0, stream>>>(Fout);
  video_seg_k<<<dim3(3, B_), blk, 0, stream>>>(Fout, score, starts, ends, vseg);

  build_qa_k<<<1728, blk, 0, stream>>>(Tout, QAB);
  seg2bf_k<<<12, blk, 0, stream>>>(vseg, tseg, A2);

  // predictor: base (per-batch) + bottom half
  gemm128<0,1,0><<<dim3(24, 1), blk, 0, stream>>>(A2, wp1tt, bp1, baseb, D4_, B_, D4_, 1536);
  gemm256<1,0,1><<<dim3(12, 18), blk5, 0, stream>>>(QAB, wp1bt, baseb, hidp, D4_, RA_, D4_, 1536);
  gemm128<0,0,0><<<dim3(6, 36), blk, 0, stream>>>(hidp, wp2t, bp2, xall, D_, RA_, D_, D4_);

  // GRU unrolled
  gather_h_k<<<72, blk, 0, stream>>>(xall, label, state0, Hbf);
  gemm128<0,0,0><<<dim3(18, 36), blk, 0, stream>>>(xall, wiht, b_ih, gib, G3_, RA_, G3_, D_);
  gemm128<0,0,0><<<dim3(18, 2), blk, 0, stream>>>(Hbf, whht, b_hh, ghb, G3_, RH_, G3_, D_);
  gru_gates_k<<<1728, blk, 0, stream>>>(gib, ghb, Hbf, hnew);
  gemm128<1,0,0><<<dim3(6, 36), blk, 0, stream>>>(hnew, wq1t, bq1, t1, D_, RA_, D_, D_);
  logits_k<<<RA_ / 4, blk, 0, stream>>>(t1, wq2, bq2, logits);
  loss_k<<<1, blk, 0, stream>>>(logits, label, (float*)d_out);
}

// Round 4
// 758.248 us; speedup vs baseline: 1.6584x; 1.0329x over previous
//
#include <hip/hip_runtime.h>
#include <hip/hip_bf16.h>
#include <math.h>

#define B_ 16
#define T_ 1024
#define P_ 48
#define S_ 12
#define A_ 24
#define D_ 768
#define D4_ 3072
#define G3_ 2304
#define RV_ (B_*T_)      // 16384
#define RP_ (B_*P_)      // 768
#define RA_ (B_*S_*A_)   // 4608
#define RH_ (B_*S_)      // 192
#define RPB_ 288         // rows per batch in RA_

typedef float f32x4 __attribute__((ext_vector_type(4)));
typedef short s16x8 __attribute__((ext_vector_type(8)));

__device__ __forceinline__ unsigned short f2bf(float f) {
  unsigned int u = __float_as_uint(f);
  u += 0x7FFF + ((u >> 16) & 1);   // RNE
  return (unsigned short)(u >> 16);
}
__device__ __forceinline__ unsigned int pk2(float lo, float hi) {
  return (unsigned int)f2bf(lo) | ((unsigned int)f2bf(hi) << 16);
}
__device__ __forceinline__ float bf2f(unsigned short u) {
  return __uint_as_float(((unsigned int)u) << 16);
}
__device__ __forceinline__ void gload16(const void* g, void* l) {
  __builtin_amdgcn_global_load_lds((const __attribute__((address_space(1))) void*)g,
                                   (__attribute__((address_space(3))) void*)l, 16, 0, 0);
}
__device__ __forceinline__ int xcd_swizzle(int orig, int nwg) {
  int q = nwg >> 3, r = nwg & 7;
  int xcd = orig & 7, local = orig >> 3;
  return (xcd < r ? xcd * (q + 1) : r * (q + 1) + (xcd - r) * q) + local;
}

// ============ gemmdb: 128x128 tile, BK=64, 4 waves, double-buffered 2-phase ============
// C = act(A[M,K] @ Wt[N,K]^T + bias). K%64==0, N%128==0, M arbitrary.
// OUT: 0=bf16->C0  1=f32->C0  2=split rows (bf16; row<splitrow->C0 else C1)  3=no store, logits
// B2D: bias is [B_][N] f32 indexed by row/RPB_
template<int ACT, int OUT, int B2D>
__global__ __launch_bounds__(256, 2)
void gemmdb(const unsigned short* __restrict__ A,
            const unsigned short* __restrict__ Wt,
            const float* __restrict__ bias,
            void* __restrict__ C0, int ldc0,
            void* __restrict__ C1, int ldc1, int splitrow,
            const float* __restrict__ wq2v, float* __restrict__ logits,
            int M, int N, int K)
{
  __shared__ __align__(16) unsigned short As[2][8192];   // [buf][128 rows][64 k]
  __shared__ __align__(16) unsigned short Bs[2][8192];
  const int tid  = threadIdx.x;
  const int lane = tid & 63;
  const int wid  = tid >> 6;
  const int wm = (wid >> 1) * 64, wn = (wid & 1) * 64;
  const int gx = gridDim.x;
  int swz = xcd_swizzle(blockIdx.y * gx + blockIdx.x, gx * gridDim.y);
  const int bm0 = (swz / gx) * 128, bn0 = (swz % gx) * 128;

  // staging: chunk c covers rows wid*32 + c*8 + (lane>>3), k-seg (lane&7)*8
  const int srow = wid * 32 + (lane >> 3);
  const int skk  = (lane & 7) * 8;
  const unsigned short* gA[4];
  const unsigned short* gB[4];
#pragma unroll
  for (int c = 0; c < 4; ++c) {
    int r = bm0 + srow + c * 8; if (r > M - 1) r = M - 1;
    gA[c] = A  + (size_t)r * K + skk;
    gB[c] = Wt + (size_t)(bn0 + srow + c * 8) * K + skk;
  }

  f32x4 acc[4][4] = {};
  const int fr = lane & 15, fq = lane >> 4;
  const int nt = K / 64;

#pragma unroll
  for (int c = 0; c < 4; ++c) {
    gload16(gA[c], &As[0][wid * 2048 + c * 512]);
    gload16(gB[c], &Bs[0][wid * 2048 + c * 512]);
  }
  __syncthreads();

  for (int t = 0; t < nt; ++t) {
    if (t + 1 < nt) {
      const int nb = (t + 1) & 1;
      const int ko = (t + 1) * 64;
#pragma unroll
      for (int c = 0; c < 4; ++c) {
        gload16(gA[c] + ko, &As[nb][wid * 2048 + c * 512]);
        gload16(gB[c] + ko, &Bs[nb][wid * 2048 + c * 512]);
      }
    }
    const int cb = t & 1;
#pragma unroll
    for (int ks = 0; ks < 2; ++ks) {
      s16x8 af[4], bf4[4];
#pragma unroll
      for (int i = 0; i < 4; ++i) {
        af[i]  = *(const s16x8*)(&As[cb][(wm + i * 16 + fr) * 64 + ks * 32 + fq * 8]);
        bf4[i] = *(const s16x8*)(&Bs[cb][(wn + i * 16 + fr) * 64 + ks * 32 + fq * 8]);
      }
#pragma unroll
      for (int mi = 0; mi < 4; ++mi)
#pragma unroll
        for (int ni = 0; ni < 4; ++ni)
          acc[mi][ni] = __builtin_amdgcn_mfma_f32_16x16x32_bf16(af[mi], bf4[ni], acc[mi][ni], 0, 0, 0);
    }
    __syncthreads();   // drains vmcnt (next tile staged) + cur-buf reads done
  }

  if (OUT == 3) {
    // fused logits: part[row] = sum_col relu(acc+bias)*wq2[col]; reduce over fr lanes
#pragma unroll
    for (int mi = 0; mi < 4; ++mi)
#pragma unroll
      for (int r = 0; r < 4; ++r) {
        int row = bm0 + wm + mi * 16 + fq * 4 + r;
        float part = 0.f;
#pragma unroll
        for (int ni = 0; ni < 4; ++ni) {
          int col = bn0 + wn + ni * 16 + fr;
          float v = acc[mi][ni][r] + bias[col];
          v = fmaxf(v, 0.f);
          part += v * wq2v[col];
        }
        part += __shfl_xor(part, 1);
        part += __shfl_xor(part, 2);
        part += __shfl_xor(part, 4);
        part += __shfl_xor(part, 8);
        if (fr == 0 && row < M) atomicAdd(&logits[row], part);
      }
  } else {
#pragma unroll
    for (int ni = 0; ni < 4; ++ni) {
      int col = bn0 + wn + ni * 16 + fr;
      float bb = B2D ? 0.f : bias[col];
#pragma unroll
      for (int mi = 0; mi < 4; ++mi)
#pragma unroll
        for (int r = 0; r < 4; ++r) {
          int row = bm0 + wm + mi * 16 + fq * 4 + r;
          if (row < M) {
            float v = acc[mi][ni][r] + (B2D ? bias[(size_t)(row / RPB_) * N + col] : bb);
            if (ACT) v = fmaxf(v, 0.f);
            if (OUT == 1)      ((float*)C0)[(size_t)row * ldc0 + col] = v;
            else if (OUT == 2) {
              if (row < splitrow) ((unsigned short*)C0)[(size_t)row * ldc0 + col] = f2bf(v);
              else ((unsigned short*)C1)[(size_t)(row - splitrow) * ldc1 + col] = f2bf(v);
            } else             ((unsigned short*)C0)[(size_t)row * ldc0 + col] = f2bf(v);
          }
        }
    }
  }
}

// ============ merged transposes (10 jobs) + paras softmax ============
struct TPtrs { const float* s[10]; unsigned short* d[10]; };

__global__ void transpose_all_k(TPtrs p, const float* __restrict__ ps, float* __restrict__ score) {
  constexpr int KN[10][2] = {{768,768},{768,768},{768,768},{768,768},{768,768},
                             {1536,3072},{1536,3072},{3072,768},{768,2304},{768,2304}};
  constexpr int TC[10] = {576,576,576,576,576,4608,4608,2304,1728,1728};  // (N/32)*(K/32)
  int bid = blockIdx.x;
  if (bid == 17856) {   // softmax over P per b (4 waves x 4 reps)
    int lane = threadIdx.x & 63, g = threadIdx.x >> 6;
#pragma unroll
    for (int rep = 0; rep < 4; ++rep) {
      int b = rep * 4 + g;
      float v = (lane < P_) ? ps[b * P_ + lane] : -INFINITY;
      float m = v;
      for (int o = 32; o > 0; o >>= 1) m = fmaxf(m, __shfl_xor(m, o));
      float e = (lane < P_) ? __expf(v - m) : 0.f;
      float s = e;
      for (int o = 32; o > 0; o >>= 1) s += __shfl_xor(s, o);
      if (lane < P_) score[b * P_ + lane] = e / s;
    }
    return;
  }
  int j = 0, local = bid;
  while (local >= TC[j]) { local -= TC[j]; ++j; }
  const int K = KN[j][0], N = KN[j][1];
  const float* W = p.s[j];
  unsigned short* Wt = p.d[j];
  int tx = local % (N >> 5), ty = local / (N >> 5);
  __shared__ float t[32][33];
  int n0 = tx * 32, k0 = ty * 32;
  int c = threadIdx.x & 31, r8 = threadIdx.x >> 5;
#pragma unroll
  for (int i = 0; i < 4; ++i) {
    int r = r8 + i * 8;
    t[r][c] = W[(size_t)(k0 + r) * N + n0 + c];
  }
  __syncthreads();
#pragma unroll
  for (int i = 0; i < 4; ++i) {
    int r = r8 + i * 8;
    Wt[(size_t)(n0 + r) * K + k0 + c] = f2bf(t[c][r]);
  }
}

// ============ pack f32->bf16 (5 inputs) + segment weights w[b,t] (+ zero vseg) ============
__global__ void pack_segw_k(const float* __restrict__ video, const float* __restrict__ abut,
                            const float* __restrict__ para, const float* __restrict__ atex,
                            const float* __restrict__ quest,
                            unsigned short* __restrict__ Vcat, unsigned short* __restrict__ Tcat,
                            const float* __restrict__ score, const int* __restrict__ starts,
                            const int* __restrict__ ends, float* __restrict__ w,
                            float* __restrict__ vseg) {
  int blk = blockIdx.x;
  if (blk < 9894) {
    int idx = blk * 256 + threadIdx.x;
    int r = idx / 96, d8 = (idx % 96) * 8;
    const float* src; unsigned short* dst;
    if (r < 16384)      { src = video + (size_t)r * D_;           dst = Vcat + (size_t)r * D_; }
    else if (r < 20992) { src = abut + (size_t)(r - 16384) * D_;  dst = Vcat + (size_t)r * D_; }
    else if (r < 21760) { src = para + (size_t)(r - 20992) * D_;  dst = Tcat + (size_t)(r - 20992) * D_; }
    else if (r < 26368) { src = atex + (size_t)(r - 21760) * D_;  dst = Tcat + (size_t)(r - 20992) * D_; }
    else                { src = quest + (size_t)(r - 26368) * D_; dst = Tcat + (size_t)(r - 20992) * D_; }
    float4 a = *(const float4*)(src + d8);
    float4 b = *(const float4*)(src + d8 + 4);
    uint4 pk; pk.x = pk2(a.x, a.y); pk.y = pk2(a.z, a.w); pk.z = pk2(b.x, b.y); pk.w = pk2(b.z, b.w);
    *(uint4*)(dst + d8) = pk;
  } else {
    int idx = (blk - 9894) * 256 + threadIdx.x;   // [0, 16384)
    int b = idx >> 10, t = idx & 1023;
    float acc = 0.f;
    for (int p = 0; p < P_; ++p) {
      int s = starts[b * P_ + p], e = ends[b * P_ + p];
      float sc = score[b * P_ + p];
      if (s >= e) { if (t == s) acc += sc; }
      else if (t >= s && t < e) acc += sc / (float)(e - s);
    }
    w[idx] = acc;
    if (idx < B_ * D_) vseg[idx] = 0.f;
  }
}

// ============ vseg (weighted sum of Vv rows, atomic) + tseg (weighted sum of Tout) ============
__global__ void redwsum_k(const unsigned short* __restrict__ Vv, const float* __restrict__ w,
                          float* __restrict__ vseg, const float* __restrict__ Tout,
                          const float* __restrict__ score, float* __restrict__ tseg) {
  int blk = blockIdx.x, tid = threadIdx.x;
  if (blk < 128) {
    int b = blk >> 3, tc = blk & 7;
    const unsigned short* base = Vv + ((size_t)b * T_ + tc * 128) * D_;
    const float* wp = w + b * T_ + tc * 128;
    float a0 = 0.f, a1 = 0.f, a2 = 0.f;
    for (int t = 0; t < 128; ++t) {
      float wt = wp[t];
      if (wt != 0.f) {
        const unsigned short* rp = base + (size_t)t * D_;
        a0 += wt * bf2f(rp[tid]);
        a1 += wt * bf2f(rp[tid + 256]);
        a2 += wt * bf2f(rp[tid + 512]);
      }
    }
    atomicAdd(&vseg[b * D_ + tid],       a0);
    atomicAdd(&vseg[b * D_ + tid + 256], a1);
    atomicAdd(&vseg[b * D_ + tid + 512], a2);
  } else {
    int i = blk - 128;            // 48 blocks: b*3 + x
    int b = i / 3, d = (i % 3) * 256 + tid;
    float acc = 0.f;
    for (int p = 0; p < P_; ++p)
      acc += score[b * P_ + p] * Tout[((size_t)b * P_ + p) * D_ + d];
    tseg[b * D_ + d] = acc;
  }
}

// ============ QAB[:, 0:768) = bf16(at+q)  +  A2 = bf16(vseg||tseg) ============
__global__ void qa_seg_k(const float* __restrict__ Tout, unsigned short* __restrict__ QAB,
                         const float* __restrict__ vseg, const float* __restrict__ tseg,
                         unsigned short* __restrict__ A2) {
  int blk = blockIdx.x;
  if (blk < 1728) {
    int idx = blk * 256 + threadIdx.x;
    int m = idx / 96, d8 = (idx % 96) * 8;
    int b = m / RPB_;
    const float* at = Tout + (size_t)(RP_ + m) * D_ + d8;
    const float* qq = Tout + (size_t)(RP_ + RA_ + b) * D_ + d8;
    uint4 p;
    p.x = pk2(at[0] + qq[0], at[1] + qq[1]);
    p.y = pk2(at[2] + qq[2], at[3] + qq[3]);
    p.z = pk2(at[4] + qq[4], at[5] + qq[5]);
    p.w = pk2(at[6] + qq[6], at[7] + qq[7]);
    *(uint4*)(QAB + (size_t)m * 1536 + d8) = p;
  } else {
    int idx = (blk - 1728) * 256 + threadIdx.x;   // 16*192
    int b = idx / 192, seg = (idx % 192) * 8;
    const float* src = (seg < D_) ? (vseg + b * D_ + seg) : (tseg + b * D_ + seg - D_);
    float4 a = *(const float4*)src;
    float4 c = *(const float4*)(src + 4);
    uint4 p; p.x = pk2(a.x, a.y); p.y = pk2(a.z, a.w); p.z = pk2(c.x, c.y); p.w = pk2(c.z, c.w);
    *(uint4*)(A2 + (size_t)b * 1536 + seg) = p;
  }
}

// ============ gather H + init logits with bq2 ============
__global__ void gatherz_k(const unsigned short* __restrict__ xall, const int* __restrict__ label,
                          const float* __restrict__ state0, unsigned short* __restrict__ H,
                          const float* __restrict__ bq2, float* __restrict__ logits) {
  int idx = blockIdx.x * 256 + threadIdx.x;     // 18432 = RH_*96
  if (idx < RA_) logits[idx] = bq2[0];
  int m = idx / 96, d8 = (idx % 96) * 8;
  int b = m / S_, s = m % S_;
  if (s == 0) {
    float4 a = *(const float4*)(state0 + d8);
    float4 c = *(const float4*)(state0 + d8 + 4);
    uint4 p; p.x = pk2(a.x, a.y); p.y = pk2(a.z, a.w); p.z = pk2(c.x, c.y); p.w = pk2(c.z, c.w);
    *(uint4*)(H + (size_t)m * D_ + d8) = p;
  } else {
    int lab = label[b * S_ + (s - 1)];
    const unsigned short* src = xall + (((size_t)b * S_ + (s - 1)) * A_ + lab) * D_ + d8;
    *(uint4*)(H + (size_t)m * D_ + d8) = *(const uint4*)src;
  }
}

__global__ void gru_gates_k(const unsigned short* __restrict__ gi, const unsigned short* __restrict__ gh,
                            const unsigned short* __restrict__ H, unsigned short* __restrict__ hnew) {
  int idx = blockIdx.x * 256 + threadIdx.x;     // RA_*96
  int m = idx / 96, d8 = (idx % 96) * 8;
  int bs = m / A_;
  const unsigned short* gim = gi + (size_t)m * G3_;
  const unsigned short* ghm = gh + (size_t)bs * G3_;
  s16x8 ir8 = *(const s16x8*)(gim + d8);
  s16x8 iz8 = *(const s16x8*)(gim + D_ + d8);
  s16x8 in8 = *(const s16x8*)(gim + 2 * D_ + d8);
  s16x8 hr8 = *(const s16x8*)(ghm + d8);
  s16x8 hz8 = *(const s16x8*)(ghm + D_ + d8);
  s16x8 hn8 = *(const s16x8*)(ghm + 2 * D_ + d8);
  s16x8 h8  = *(const s16x8*)(H + (size_t)bs * D_ + d8);
  s16x8 o;
#pragma unroll
  for (int j = 0; j < 8; ++j) {
    float r = 1.f / (1.f + __expf(-(bf2f((unsigned short)ir8[j]) + bf2f((unsigned short)hr8[j]))));
    float z = 1.f / (1.f + __expf(-(bf2f((unsigned short)iz8[j]) + bf2f((unsigned short)hz8[j]))));
    float n = tanhf(bf2f((unsigned short)in8[j]) + r * bf2f((unsigned short)hn8[j]));
    float h = bf2f((unsigned short)h8[j]);
    o[j] = (short)f2bf((1.f - z) * n + z * h);
  }
  *(s16x8*)(hnew + (size_t)m * D_ + d8) = o;
}

__global__ void loss_k(const float* __restrict__ logits, const int* __restrict__ label,
                       float* __restrict__ out) {
  __shared__ float red[256];
  int tid = threadIdx.x;
  float ls = 0.f;
  if (tid < RH_) {
    const float* lg = logits + (size_t)tid * A_;
    float mx = -INFINITY;
    for (int a = 0; a < A_; ++a) mx = fmaxf(mx, lg[a]);
    float sum = 0.f;
    for (int a = 0; a < A_; ++a) sum += __expf(lg[a] - mx);
    ls = (logf(sum) + mx) - lg[label[tid]];
  }
  red[tid] = ls;
  for (int o = 128; o > 0; o >>= 1) {
    __syncthreads();
    if (tid < o) red[tid] += red[tid + o];
  }
  if (tid == 0) out[0] = red[0] / (float)RH_;
}

extern "C" void kernel_launch(void* const* d_in, const int* in_sizes, int n_in,
                              void* d_out, int out_size, void* d_ws, size_t ws_size,
                              hipStream_t stream) {
  (void)in_sizes; (void)n_in; (void)out_size; (void)ws_size;
  const float* video      = (const float*)d_in[0];
  const float* para       = (const float*)d_in[1];
  const float* question   = (const float*)d_in[2];
  const float* a_texts    = (const float*)d_in[3];
  const float* a_buttons  = (const float*)d_in[4];
  const float* paras_score= (const float*)d_in[5];
  const int*   starts     = (const int*)d_in[6];
  const int*   ends       = (const int*)d_in[7];
  const int*   label      = (const int*)d_in[8];
  const float* wv1 = (const float*)d_in[9];  const float* bv1 = (const float*)d_in[10];
  const float* wv2 = (const float*)d_in[11]; const float* bv2 = (const float*)d_in[12];
  const float* wt1 = (const float*)d_in[13]; const float* bt1 = (const float*)d_in[14];
  const float* wt2 = (const float*)d_in[15]; const float* bt2 = (const float*)d_in[16];
  const float* wp1 = (const float*)d_in[17]; const float* bp1 = (const float*)d_in[18];
  const float* wp2 = (const float*)d_in[19]; const float* bp2 = (const float*)d_in[20];
  const float* w_ih= (const float*)d_in[21]; const float* b_ih= (const float*)d_in[22];
  const float* w_hh= (const float*)d_in[23]; const float* b_hh= (const float*)d_in[24];
  const float* wq1 = (const float*)d_in[25]; const float* bq1 = (const float*)d_in[26];
  const float* wq2 = (const float*)d_in[27]; const float* bq2 = (const float*)d_in[28];
  const float* state0 = (const float*)d_in[29];

  char* base = (char*)d_ws;
  unsigned short* wt1t = (unsigned short*)(base + 0);
  unsigned short* wt2t = (unsigned short*)(base + 1179648);
  unsigned short* wv1t = (unsigned short*)(base + 2359296);
  unsigned short* wv2t = (unsigned short*)(base + 3538944);
  unsigned short* wq1t = (unsigned short*)(base + 4718592);
  unsigned short* wp1tt= (unsigned short*)(base + 5898240);    // [3072,1536]
  unsigned short* wp1bt= (unsigned short*)(base + 15335424);   // [3072,1536]
  unsigned short* wp2t = (unsigned short*)(base + 24772608);   // [768,3072]
  unsigned short* wiht = (unsigned short*)(base + 29491200);   // [2304,768]
  unsigned short* whht = (unsigned short*)(base + 33030144);
  unsigned short* Vcat = (unsigned short*)(base + 36569088);   // [20992,768] -> later Vv, then gib
  unsigned short* Vv   = Vcat;                                 // [16384,768] (Vcat dead after mlpV L1)
  unsigned short* gib  = Vcat;                                 // [4608,2304] (Vv dead after redwsum)
  unsigned short* Tcat = (unsigned short*)(base + 68812800);   // [5392,768]
  unsigned short* Hid  = (unsigned short*)(base + 77094912);   // [20992,768] -> later hidp
  unsigned short* hidp = Hid;                                  // [4608,3072]
  float*          Tout = (float*)(base + 109338624);           // [5392,768] f32
  unsigned short* QAB  = (unsigned short*)(base + 125902848);  // [4608,1536] -> later hnew
  unsigned short* hnew = QAB;                                  // [4608,768]
  unsigned short* xall = (unsigned short*)(base + 140058624);  // [4608,768]
  unsigned short* ghb  = (unsigned short*)(base + 147136512);  // [192,2304]
  char* sm = base + 148021248;
  float* wseg   = (float*)(sm + 0);         // [16,1024]
  float* score  = (float*)(sm + 65536);
  float* tseg   = (float*)(sm + 69632);
  float* vseg   = (float*)(sm + 118784);
  unsigned short* A2 = (unsigned short*)(sm + 167936);
  float* baseb  = (float*)(sm + 217088);    // [16,3072]
  unsigned short* Hbf = (unsigned short*)(sm + 413696);
  float* logits = (float*)(sm + 708608);

  dim3 blk(256);
  TPtrs tp;
  tp.s[0] = wt1; tp.d[0] = wt1t;
  tp.s[1] = wt2; tp.d[1] = wt2t;
  tp.s[2] = wv1; tp.d[2] = wv1t;
  tp.s[3] = wv2; tp.d[3] = wv2t;
  tp.s[4] = wq1; tp.d[4] = wq1t;
  tp.s[5] = wp1;                  tp.d[5] = wp1tt;
  tp.s[6] = wp1 + 1536 * D4_;     tp.d[6] = wp1bt;
  tp.s[7] = wp2; tp.d[7] = wp2t;
  tp.s[8] = w_ih; tp.d[8] = wiht;
  tp.s[9] = w_hh; tp.d[9] = whht;

  // 1. transposes + softmax
  transpose_all_k<<<17857, blk, 0, stream>>>(tp, paras_score, score);
  // 2. pack inputs + segment weights (+zero vseg)
  pack_segw_k<<<9958, blk, 0, stream>>>(video, a_buttons, para, a_texts, question,
                                        Vcat, Tcat, score, starts, ends, wseg, vseg);
  // 3-4. MLP_t chain [para; a_texts; question] = 5392 rows
  gemmdb<1,0,0><<<dim3(6, 43), blk, 0, stream>>>(Tcat, wt1t, bt1, Hid, D_, nullptr, 0, 0,
                                                 nullptr, nullptr, 5392, D_, D_);
  gemmdb<0,1,0><<<dim3(6, 43), blk, 0, stream>>>(Hid, wt2t, bt2, Tout, D_, nullptr, 0, 0,
                                                 nullptr, nullptr, 5392, D_, D_);
  // 5-6. MLP_v chain [video; a_buttons] = 20992 rows; L2 split -> Vv / QAB[:,768:)
  gemmdb<1,0,0><<<dim3(6, 164), blk, 0, stream>>>(Vcat, wv1t, bv1, Hid, D_, nullptr, 0, 0,
                                                  nullptr, nullptr, 20992, D_, D_);
  gemmdb<0,2,0><<<dim3(6, 164), blk, 0, stream>>>(Hid, wv2t, bv2, Vv, D_, QAB + D_, 1536, RV_,
                                                  nullptr, nullptr, 20992, D_, D_);
  // 7. vseg (weighted video sum) + tseg (weighted para sum)
  redwsum_k<<<176, blk, 0, stream>>>(Vv, wseg, vseg, Tout, score, tseg);
  // 8. QAB qa-half + A2
  qa_seg_k<<<1740, blk, 0, stream>>>(Tout, QAB, vseg, tseg, A2);
  // 9. baseb = A2 @ wp1_top + bp1   [16,3072] f32
  gemmdb<0,1,0><<<dim3(24, 1), blk, 0, stream>>>(A2, wp1tt, bp1, baseb, D4_, nullptr, 0, 0,
                                                 nullptr, nullptr, B_, D4_, 1536);
  // 10. hidp = relu(QAB @ wp1_bot + baseb[b])
  gemmdb<1,0,1><<<dim3(24, 36), blk, 0, stream>>>(QAB, wp1bt, baseb, hidp, D4_, nullptr, 0, 0,
                                                  nullptr, nullptr, RA_, D4_, 1536);
  // 11. xall = hidp @ wp2 + bp2
  gemmdb<0,0,0><<<dim3(6, 36), blk, 0, stream>>>(hidp, wp2t, bp2, xall, D_, nullptr, 0, 0,
                                                 nullptr, nullptr, RA_, D_, D4_);
  // 12. gather H + init logits
  gatherz_k<<<72, blk, 0, stream>>>(xall, label, state0, Hbf, bq2, logits);
  // 13. gi = xall @ w_ih + b_ih
  gemmdb<0,0,0><<<dim3(18, 36), blk, 0, stream>>>(xall, wiht, b_ih, gib, G3_, nullptr, 0, 0,
                                                  nullptr, nullptr, RA_, G3_, D_);
  // 14. gh = Hbf @ w_hh + b_hh
  gemmdb<0,0,0><<<dim3(18, 2), blk, 0, stream>>>(Hbf, whht, b_hh, ghb, G3_, nullptr, 0, 0,
                                                 nullptr, nullptr, RH_, G3_, D_);
  // 15. gates -> hnew
  gru_gates_k<<<1728, blk, 0, stream>>>(gib, ghb, Hbf, hnew);
  // 16. wq1 GEMM with fused logits (no t1 store)
  gemmdb<1,3,0><<<dim3(6, 36), blk, 0, stream>>>(hnew, wq1t, bq1, nullptr, 0, nullptr, 0, 0,
                                                 wq2, logits, RA_, D_, D_);
  // 17. loss
  loss_k<<<1, blk, 0, stream>>>(logits, label, (float*)d_out);
}

// Round 9
// 706.095 us; speedup vs baseline: 1.7809x; 1.0739x over previous
//
#include <hip/hip_runtime.h>
#include <hip/hip_bf16.h>
#include <math.h>

#define B_ 16
#define T_ 1024
#define P_ 48
#define S_ 12
#define A_ 24
#define D_ 768
#define D4_ 3072
#define G3_ 2304
#define RV_ (B_*T_)      // 16384
#define RP_ (B_*P_)      // 768
#define RA_ (B_*S_*A_)   // 4608
#define RH_ (B_*S_)      // 192
#define RPB_ 288

typedef float f32x4 __attribute__((ext_vector_type(4)));
typedef short s16x8 __attribute__((ext_vector_type(8)));

__device__ __forceinline__ unsigned short f2bf(float f) {
  unsigned int u = __float_as_uint(f);
  u += 0x7FFF + ((u >> 16) & 1);
  return (unsigned short)(u >> 16);
}
__device__ __forceinline__ unsigned int pk2(float lo, float hi) {
  return (unsigned int)f2bf(lo) | ((unsigned int)f2bf(hi) << 16);
}
__device__ __forceinline__ float bf2f(unsigned short u) {
  return __uint_as_float(((unsigned int)u) << 16);
}
__device__ __forceinline__ void gload16(const void* g, void* l) {
  __builtin_amdgcn_global_load_lds((const __attribute__((address_space(1))) void*)g,
                                   (__attribute__((address_space(3))) void*)l, 16, 0, 0);
}
__device__ __forceinline__ int xcd_swizzle(int orig, int nwg) {
  int q = nwg >> 3, r = nwg & 7;
  int xcd = orig & 7, local = orig >> 3;
  return (xcd < r ? xcd * (q + 1) : r * (q + 1) + (xcd - r) * q) + local;
}

#define VMW8 asm volatile("s_waitcnt vmcnt(8)" ::: "memory")
#define VMW4 asm volatile("s_waitcnt vmcnt(4)" ::: "memory")
#define VMW0 asm volatile("s_waitcnt vmcnt(0)" ::: "memory")

// ====================== gemmph: counted-vmcnt phased GEMM ======================
// C = act(A[M,K] @ W[N,K]^T + bias); W/bias selected per row-block (row<wsplit -> 0).
// Half-K-tile (32k) staging, 3 halves in flight, vmcnt(8) steady state, setprio MFMA.
// MODE: 0 = bf16 out (optional row-split C0/C1 at osplit)
//       2 = mlp-L2 routing: rows<16384 atomic wseg-weighted into vseg;
//           <20992 bf16 -> QAB col+768; else f32 -> Tout(row-20992)
//       3 = fused logits: atomicAdd(logits[row], sum_col relu(v)*wq2[col])
template<int BM, int BN, int TH, int ACT, int MODE, int B2D>
__global__ __launch_bounds__(TH, 2)
void gemmph(const unsigned short* __restrict__ A,
            const unsigned short* __restrict__ Wt0, const float* __restrict__ bias0,
            const unsigned short* __restrict__ Wt1, const float* __restrict__ bias1,
            int wsplit,
            void* __restrict__ C0, int ldc0,
            void* __restrict__ C1, int ldc1, int osplit,
            const float* __restrict__ xv0,   // MODE3: wq2 | MODE2: wseg
            float* __restrict__ xv1,         // MODE3: logits | MODE2: vseg
            unsigned short* __restrict__ xq, // MODE2: QAB
            float* __restrict__ xt,          // MODE2: Tout
            int M, int N, int K)
{
  constexpr int MRF = BM / 32;               // A frags per wave: 256->8, 128->4
  __shared__ __align__(16) unsigned short As[2][2][BM][32];
  __shared__ __align__(16) unsigned short Bs[2][2][BN][32];
  const int tid  = threadIdx.x;
  const int lane = tid & 63;
  const int wid  = tid >> 6;
  const int wm = (BM == 256) ? (wid >> 2) * 128 : (wid >> 1) * 64;
  const int wn = (BM == 256) ? (wid & 3) * 64   : (wid & 1) * 64;
  const int gx = gridDim.x;
  int swz = xcd_swizzle(blockIdx.y * gx + blockIdx.x, gx * gridDim.y);
  const int bm0 = (swz / gx) * BM, bn0 = (swz % gx) * BN;

  const unsigned short* W = (bm0 < wsplit) ? Wt0 : Wt1;
  const float* bias = (bm0 < wsplit) ? bias0 : bias1;

  // staging geometry: lane l of wave wid, chunk c covers row (wid*2+c)*16 + (l>>2),
  // LDS slot l&3; global k-slot = (l&3) ^ (row&3)  [read-side XOR matches]
  const int srow = (wid * 2) * 16 + (lane >> 2);   // chunk 0 row; chunk1 adds 16
  const int sslot = lane & 3;

  f32x4 acc[MRF][4] = {};
  const int fr = lane & 15, fq = lane >> 4;
  const int sws = (fq ^ (fr & 3)) * 8;             // swizzled read slot (shorts)

  auto stage = [&](int buf, int ks, int kt) {
#pragma unroll
    for (int c = 0; c < 2; ++c) {
      int r = srow + c * 16;
      int ksl = sslot ^ (r & 3);
      int ar = bm0 + r; if (ar > M - 1) ar = M - 1;
      gload16(A + (size_t)ar * K + kt * 64 + ks * 32 + ksl * 8, &As[buf][ks][(wid * 2 + c) * 16][0]);
      gload16(W + (size_t)(bn0 + r) * K + kt * 64 + ks * 32 + ksl * 8, &Bs[buf][ks][(wid * 2 + c) * 16][0]);
    }
  };

  auto compute = [&](int cb, int ks) {
    s16x8 af[MRF], bf4[4];
#pragma unroll
    for (int i = 0; i < MRF; ++i)
      af[i] = *(const s16x8*)(&As[cb][ks][wm + i * 16 + fr][sws]);
#pragma unroll
    for (int i = 0; i < 4; ++i)
      bf4[i] = *(const s16x8*)(&Bs[cb][ks][wn + i * 16 + fr][sws]);
    __builtin_amdgcn_s_setprio(1);
#pragma unroll
    for (int mi = 0; mi < MRF; ++mi)
#pragma unroll
      for (int ni = 0; ni < 4; ++ni)
        acc[mi][ni] = __builtin_amdgcn_mfma_f32_16x16x32_bf16(af[mi], bf4[ni], acc[mi][ni], 0, 0, 0);
    __builtin_amdgcn_s_setprio(0);
  };

  const int nt = K >> 6;
  stage(0, 0, 0); stage(0, 1, 0); stage(1, 0, 1);
  for (int t = 0; t < nt; ++t) {
    const int cb = t & 1;
    // phase 0: needs half (t,0)
    if (t + 1 < nt) { VMW8; __builtin_amdgcn_s_barrier(); stage(cb ^ 1, 1, t + 1); }
    else            { VMW4; __builtin_amdgcn_s_barrier(); }
    compute(cb, 0);
    // phase 1: needs half (t,1)
    if (t + 2 < nt)       { VMW8; __builtin_amdgcn_s_barrier(); stage(cb, 0, t + 2); }
    else if (t + 2 == nt) { VMW8; __builtin_amdgcn_s_barrier(); }
    else                  { VMW0; __builtin_amdgcn_s_barrier(); }
    compute(cb, 1);
  }

  // ---------------- epilogue ----------------
  if (MODE == 3) {
#pragma unroll
    for (int mi = 0; mi < MRF; ++mi)
#pragma unroll
      for (int r = 0; r < 4; ++r) {
        int row = bm0 + wm + mi * 16 + fq * 4 + r;
        float part = 0.f;
#pragma unroll
        for (int ni = 0; ni < 4; ++ni) {
          int col = bn0 + wn + ni * 16 + fr;
          float v = fmaxf(acc[mi][ni][r] + bias[col], 0.f);
          part += v * xv0[col];
        }
        part += __shfl_xor(part, 1);
        part += __shfl_xor(part, 2);
        part += __shfl_xor(part, 4);
        part += __shfl_xor(part, 8);
        if (fr == 0 && row < M) atomicAdd(&xv1[row], part);
      }
  } else if (MODE == 2 && bm0 < 16384) {
    // video rows: vseg[b,col] += sum_rows wseg[row]*v  (no store of video_v)
    float s[4] = {0.f, 0.f, 0.f, 0.f};
#pragma unroll
    for (int mi = 0; mi < MRF; ++mi)
#pragma unroll
      for (int r = 0; r < 4; ++r) {
        int row = bm0 + wm + mi * 16 + fq * 4 + r;
        float wv = xv0[row];
#pragma unroll
        for (int ni = 0; ni < 4; ++ni) {
          int col = bn0 + wn + ni * 16 + fr;
          s[ni] += wv * (acc[mi][ni][r] + bias[col]);
        }
      }
    int b = bm0 >> 10;
#pragma unroll
    for (int ni = 0; ni < 4; ++ni) {
      s[ni] += __shfl_xor(s[ni], 16);
      s[ni] += __shfl_xor(s[ni], 32);
      if (fq == 0) atomicAdd(&xv1[b * D_ + bn0 + wn + ni * 16 + fr], s[ni]);
    }
  } else {
#pragma unroll
    for (int ni = 0; ni < 4; ++ni) {
      int col = bn0 + wn + ni * 16 + fr;
      float bb = B2D ? 0.f : bias[col];
#pragma unroll
      for (int mi = 0; mi < MRF; ++mi)
#pragma unroll
        for (int r = 0; r < 4; ++r) {
          int row = bm0 + wm + mi * 16 + fq * 4 + r;
          if (row >= M) continue;
          float v = acc[mi][ni][r] + (B2D ? bias[(size_t)(row / RPB_) * N + col] : bb);
          if (ACT) v = fmaxf(v, 0.f);
          if (MODE == 2) {
            if (row < 20992) xq[(size_t)(row - 16384) * 1536 + D_ + col] = f2bf(v);
            else             xt[(size_t)(row - 20992) * D_ + col] = v;
          } else {
            if (osplit && row >= osplit) ((unsigned short*)C1)[(size_t)(row - osplit) * ldc1 + col] = f2bf(v);
            else ((unsigned short*)C0)[(size_t)row * ldc0 + col] = f2bf(v);
          }
        }
    }
  }
}

// ====================== gemmdb (r4, kept for tiny baseb GEMM; f32 out) ======================
__global__ __launch_bounds__(256, 2)
void gemmdb_f32(const unsigned short* __restrict__ A,
                const unsigned short* __restrict__ Wt,
                const float* __restrict__ bias,
                float* __restrict__ C0, int ldc0,
                int M, int N, int K)
{
  __shared__ __align__(16) unsigned short As[2][8192];
  __shared__ __align__(16) unsigned short Bs[2][8192];
  const int tid  = threadIdx.x;
  const int lane = tid & 63;
  const int wid  = tid >> 6;
  const int wm = (wid >> 1) * 64, wn = (wid & 1) * 64;
  const int bm0 = blockIdx.y * 128, bn0 = blockIdx.x * 128;
  const int srow = wid * 32 + (lane >> 3);
  const int skk  = (lane & 7) * 8;
  const unsigned short* gA[4];
  const unsigned short* gB[4];
#pragma unroll
  for (int c = 0; c < 4; ++c) {
    int r = bm0 + srow + c * 8; if (r > M - 1) r = M - 1;
    gA[c] = A  + (size_t)r * K + skk;
    gB[c] = Wt + (size_t)(bn0 + srow + c * 8) * K + skk;
  }
  f32x4 acc[4][4] = {};
  const int fr = lane & 15, fq = lane >> 4;
  const int nt = K / 64;
#pragma unroll
  for (int c = 0; c < 4; ++c) {
    gload16(gA[c], &As[0][wid * 2048 + c * 512]);
    gload16(gB[c], &Bs[0][wid * 2048 + c * 512]);
  }
  __syncthreads();
  for (int t = 0; t < nt; ++t) {
    if (t + 1 < nt) {
      const int nb = (t + 1) & 1;
      const int ko = (t + 1) * 64;
#pragma unroll
      for (int c = 0; c < 4; ++c) {
        gload16(gA[c] + ko, &As[nb][wid * 2048 + c * 512]);
        gload16(gB[c] + ko, &Bs[nb][wid * 2048 + c * 512]);
      }
    }
    const int cb = t & 1;
#pragma unroll
    for (int ks = 0; ks < 2; ++ks) {
      s16x8 af[4], bf4[4];
#pragma unroll
      for (int i = 0; i < 4; ++i) {
        af[i]  = *(const s16x8*)(&As[cb][(wm + i * 16 + fr) * 64 + ks * 32 + fq * 8]);
        bf4[i] = *(const s16x8*)(&Bs[cb][(wn + i * 16 + fr) * 64 + ks * 32 + fq * 8]);
      }
#pragma unroll
      for (int mi = 0; mi < 4; ++mi)
#pragma unroll
        for (int ni = 0; ni < 4; ++ni)
          acc[mi][ni] = __builtin_amdgcn_mfma_f32_16x16x32_bf16(af[mi], bf4[ni], acc[mi][ni], 0, 0, 0);
    }
    __syncthreads();
  }
#pragma unroll
  for (int ni = 0; ni < 4; ++ni) {
    int col = bn0 + wn + ni * 16 + fr;
    float bb = bias[col];
#pragma unroll
    for (int mi = 0; mi < 4; ++mi)
#pragma unroll
      for (int r = 0; r < 4; ++r) {
        int row = bm0 + wm + mi * 16 + fq * 4 + r;
        if (row < M) C0[(size_t)row * ldc0 + col] = acc[mi][ni][r] + bb;
      }
  }
}

// ====================== transposes + softmax ======================
struct TPtrs { const float* s[10]; unsigned short* d[10]; };

__global__ void transpose_all_k(TPtrs p, const float* __restrict__ ps, float* __restrict__ score) {
  constexpr int KN[10][2] = {{768,768},{768,768},{768,768},{768,768},{768,768},
                             {1536,3072},{1536,3072},{3072,768},{768,2304},{768,2304}};
  constexpr int TC[10] = {576,576,576,576,576,4608,4608,2304,1728,1728};
  int bid = blockIdx.x;
  if (bid == 17856) {
    int lane = threadIdx.x & 63, g = threadIdx.x >> 6;
#pragma unroll
    for (int rep = 0; rep < 4; ++rep) {
      int b = rep * 4 + g;
      float v = (lane < P_) ? ps[b * P_ + lane] : -INFINITY;
      float m = v;
      for (int o = 32; o > 0; o >>= 1) m = fmaxf(m, __shfl_xor(m, o));
      float e = (lane < P_) ? __expf(v - m) : 0.f;
      float s = e;
      for (int o = 32; o > 0; o >>= 1) s += __shfl_xor(s, o);
      if (lane < P_) score[b * P_ + lane] = e / s;
    }
    return;
  }
  int j = 0, local = bid;
  while (local >= TC[j]) { local -= TC[j]; ++j; }
  const int K = KN[j][0], N = KN[j][1];
  const float* W = p.s[j];
  unsigned short* Wt = p.d[j];
  int tx = local % (N >> 5), ty = local / (N >> 5);
  __shared__ float t[32][33];
  int n0 = tx * 32, k0 = ty * 32;
  int c = threadIdx.x & 31, r8 = threadIdx.x >> 5;
#pragma unroll
  for (int i = 0; i < 4; ++i) {
    int r = r8 + i * 8;
    t[r][c] = W[(size_t)(k0 + r) * N + n0 + c];
  }
  __syncthreads();
#pragma unroll
  for (int i = 0; i < 4; ++i) {
    int r = r8 + i * 8;
    Wt[(size_t)(n0 + r) * K + k0 + c] = f2bf(t[c][r]);
  }
}

// ====================== pack inputs + segment weights + zero vseg ======================
__global__ void pack_segw_k(const float* __restrict__ video, const float* __restrict__ abut,
                            const float* __restrict__ para, const float* __restrict__ atex,
                            const float* __restrict__ quest,
                            unsigned short* __restrict__ Acat,
                            const float* __restrict__ score, const int* __restrict__ starts,
                            const int* __restrict__ ends, float* __restrict__ w,
                            float* __restrict__ vseg) {
  int blk = blockIdx.x;
  if (blk < 9894) {
    int idx = blk * 256 + threadIdx.x;
    int r = idx / 96, d8 = (idx % 96) * 8;
    const float* src;
    if (r < 16384)      src = video + (size_t)r * D_;
    else if (r < 20992) src = abut + (size_t)(r - 16384) * D_;
    else if (r < 21760) src = para + (size_t)(r - 20992) * D_;
    else if (r < 26368) src = atex + (size_t)(r - 21760) * D_;
    else                src = quest + (size_t)(r - 26368) * D_;
    float4 a = *(const float4*)(src + d8);
    float4 b = *(const float4*)(src + d8 + 4);
    uint4 pk; pk.x = pk2(a.x, a.y); pk.y = pk2(a.z, a.w); pk.z = pk2(b.x, b.y); pk.w = pk2(b.z, b.w);
    *(uint4*)(Acat + (size_t)r * D_ + d8) = pk;
  } else {
    int idx = (blk - 9894) * 256 + threadIdx.x;
    int b = idx >> 10, t = idx & 1023;
    float acc = 0.f;
    for (int p = 0; p < P_; ++p) {
      int s = starts[b * P_ + p], e = ends[b * P_ + p];
      float sc = score[b * P_ + p];
      if (s >= e) { if (t == s) acc += sc; }
      else if (t >= s && t < e) acc += sc / (float)(e - s);
    }
    w[idx] = acc;
    if (idx < B_ * D_) vseg[idx] = 0.f;
  }
}

// ====================== tseg reduction over Tout para rows ======================
__global__ void tseg_k(const float* __restrict__ Tout, const float* __restrict__ score,
                       float* __restrict__ tseg) {
  int i = blockIdx.x;                   // 48: b*3 + x
  int b = i / 3, d = (i % 3) * 256 + threadIdx.x;
  float acc = 0.f;
  for (int p = 0; p < P_; ++p)
    acc += score[b * P_ + p] * Tout[((size_t)b * P_ + p) * D_ + d];
  tseg[b * D_ + d] = acc;
}

// ====================== QAB qa-half + A2 ======================
__global__ void qa_seg_k(const float* __restrict__ Tout, unsigned short* __restrict__ QAB,
                         const float* __restrict__ vseg, const float* __restrict__ tseg,
                         unsigned short* __restrict__ A2) {
  int blk = blockIdx.x;
  if (blk < 1728) {
    int idx = blk * 256 + threadIdx.x;
    int m = idx / 96, d8 = (idx % 96) * 8;
    int b = m / RPB_;
    const float* at = Tout + (size_t)(RP_ + m) * D_ + d8;
    const float* qq = Tout + (size_t)(RP_ + RA_ + b) * D_ + d8;
    uint4 p;
    p.x = pk2(at[0] + qq[0], at[1] + qq[1]);
    p.y = pk2(at[2] + qq[2], at[3] + qq[3]);
    p.z = pk2(at[4] + qq[4], at[5] + qq[5]);
    p.w = pk2(at[6] + qq[6], at[7] + qq[7]);
    *(uint4*)(QAB + (size_t)m * 1536 + d8) = p;
  } else {
    int idx = (blk - 1728) * 256 + threadIdx.x;
    int b = idx / 192, seg = (idx % 192) * 8;
    const float* src = (seg < D_) ? (vseg + b * D_ + seg) : (tseg + b * D_ + seg - D_);
    float4 a = *(const float4*)src;
    float4 c = *(const float4*)(src + 4);
    uint4 p; p.x = pk2(a.x, a.y); p.y = pk2(a.z, a.w); p.z = pk2(c.x, c.y); p.w = pk2(c.z, c.w);
    *(uint4*)(A2 + (size_t)b * 1536 + seg) = p;
  }
}

// ====================== gather H + logits init ======================
__global__ void gatherz_k(const unsigned short* __restrict__ xall, const int* __restrict__ label,
                          const float* __restrict__ state0, unsigned short* __restrict__ H,
                          const float* __restrict__ bq2, float* __restrict__ logits) {
  int idx = blockIdx.x * 256 + threadIdx.x;
  if (idx < RA_) logits[idx] = bq2[0];
  int m = idx / 96, d8 = (idx % 96) * 8;
  int b = m / S_, s = m % S_;
  if (s == 0) {
    float4 a = *(const float4*)(state0 + d8);
    float4 c = *(const float4*)(state0 + d8 + 4);
    uint4 p; p.x = pk2(a.x, a.y); p.y = pk2(a.z, a.w); p.z = pk2(c.x, c.y); p.w = pk2(c.z, c.w);
    *(uint4*)(H + (size_t)m * D_ + d8) = p;
  } else {
    int lab = label[b * S_ + (s - 1)];
    const unsigned short* src = xall + (((size_t)b * S_ + (s - 1)) * A_ + lab) * D_ + d8;
    *(uint4*)(H + (size_t)m * D_ + d8) = *(const uint4*)src;
  }
}

__global__ void gru_gates_k(const unsigned short* __restrict__ gi, const unsigned short* __restrict__ gh,
                            const unsigned short* __restrict__ H, unsigned short* __restrict__ hnew) {
  int idx = blockIdx.x * 256 + threadIdx.x;
  int m = idx / 96, d8 = (idx % 96) * 8;
  int bs = m / A_;
  const unsigned short* gim = gi + (size_t)m * G3_;
  const unsigned short* ghm = gh + (size_t)bs * G3_;
  s16x8 ir8 = *(const s16x8*)(gim + d8);
  s16x8 iz8 = *(const s16x8*)(gim + D_ + d8);
  s16x8 in8 = *(const s16x8*)(gim + 2 * D_ + d8);
  s16x8 hr8 = *(const s16x8*)(ghm + d8);
  s16x8 hz8 = *(const s16x8*)(ghm + D_ + d8);
  s16x8 hn8 = *(const s16x8*)(ghm + 2 * D_ + d8);
  s16x8 h8  = *(const s16x8*)(H + (size_t)bs * D_ + d8);
  s16x8 o;
#pragma unroll
  for (int j = 0; j < 8; ++j) {
    float r = 1.f / (1.f + __expf(-(bf2f((unsigned short)ir8[j]) + bf2f((unsigned short)hr8[j]))));
    float z = 1.f / (1.f + __expf(-(bf2f((unsigned short)iz8[j]) + bf2f((unsigned short)hz8[j]))));
    float n = tanhf(bf2f((unsigned short)in8[j]) + r * bf2f((unsigned short)hn8[j]));
    float h = bf2f((unsigned short)h8[j]);
    o[j] = (short)f2bf((1.f - z) * n + z * h);
  }
  *(s16x8*)(hnew + (size_t)m * D_ + d8) = o;
}

__global__ void loss_k(const float* __restrict__ logits, const int* __restrict__ label,
                       float* __restrict__ out) {
  __shared__ float red[256];
  int tid = threadIdx.x;
  float ls = 0.f;
  if (tid < RH_) {
    const float* lg = logits + (size_t)tid * A_;
    float mx = -INFINITY;
    for (int a = 0; a < A_; ++a) mx = fmaxf(mx, lg[a]);
    float sum = 0.f;
    for (int a = 0; a < A_; ++a) sum += __expf(lg[a] - mx);
    ls = (logf(sum) + mx) - lg[label[tid]];
  }
  red[tid] = ls;
  for (int o = 128; o > 0; o >>= 1) {
    __syncthreads();
    if (tid < o) red[tid] += red[tid + o];
  }
  if (tid == 0) out[0] = red[0] / (float)RH_;
}

extern "C" void kernel_launch(void* const* d_in, const int* in_sizes, int n_in,
                              void* d_out, int out_size, void* d_ws, size_t ws_size,
                              hipStream_t stream) {
  (void)in_sizes; (void)n_in; (void)out_size; (void)ws_size;
  const float* video      = (const float*)d_in[0];
  const float* para       = (const float*)d_in[1];
  const float* question   = (const float*)d_in[2];
  const float* a_texts    = (const float*)d_in[3];
  const float* a_buttons  = (const float*)d_in[4];
  const float* paras_score= (const float*)d_in[5];
  const int*   starts     = (const int*)d_in[6];
  const int*   ends       = (const int*)d_in[7];
  const int*   label      = (const int*)d_in[8];
  const float* wv1 = (const float*)d_in[9];  const float* bv1 = (const float*)d_in[10];
  const float* wv2 = (const float*)d_in[11]; const float* bv2 = (const float*)d_in[12];
  const float* wt1 = (const float*)d_in[13]; const float* bt1 = (const float*)d_in[14];
  const float* wt2 = (const float*)d_in[15]; const float* bt2 = (const float*)d_in[16];
  const float* wp1 = (const float*)d_in[17]; const float* bp1 = (const float*)d_in[18];
  const float* wp2 = (const float*)d_in[19]; const float* bp2 = (const float*)d_in[20];
  const float* w_ih= (const float*)d_in[21]; const float* b_ih= (const float*)d_in[22];
  const float* w_hh= (const float*)d_in[23]; const float* b_hh= (const float*)d_in[24];
  const float* wq1 = (const float*)d_in[25]; const float* bq1 = (const float*)d_in[26];
  const float* wq2 = (const float*)d_in[27]; const float* bq2 = (const float*)d_in[28];
  const float* state0 = (const float*)d_in[29];

  char* base = (char*)d_ws;
  unsigned short* wt1t = (unsigned short*)(base + 0);
  unsigned short* wt2t = (unsigned short*)(base + 1179648);
  unsigned short* wv1t = (unsigned short*)(base + 2359296);
  unsigned short* wv2t = (unsigned short*)(base + 3538944);
  unsigned short* wq1t = (unsigned short*)(base + 4718592);
  unsigned short* wp1tt= (unsigned short*)(base + 5898240);
  unsigned short* wp1bt= (unsigned short*)(base + 15335424);
  unsigned short* wp2t = (unsigned short*)(base + 24772608);
  unsigned short* wiht = (unsigned short*)(base + 29491200);
  unsigned short* whht = (unsigned short*)(base + 33030144);
  unsigned short* Acat = (unsigned short*)(base + 36569088);   // [26384,768]
  unsigned short* Hid  = (unsigned short*)(base + 77094912);   // [26384,768] -> hidp -> gib
  unsigned short* hidp = Hid;
  unsigned short* gib  = Hid;
  float*          Tout = (float*)(base + 117620736);           // [5392,768] f32
  unsigned short* QAB  = (unsigned short*)(base + 134184960);  // [4608,1536] -> hnew
  unsigned short* hnew = QAB;
  unsigned short* xall = (unsigned short*)(base + 148340736);  // [4608,768]
  unsigned short* Hbf  = (unsigned short*)(base + 155418624);  // [192,768] right after xall
  unsigned short* ghb  = (unsigned short*)(base + 155713536);  // [192,2304]
  char* sm = base + 156598272;
  float* wseg   = (float*)(sm + 0);
  float* score  = (float*)(sm + 65536);
  float* tseg   = (float*)(sm + 68608);
  float* vseg   = (float*)(sm + 117760);
  unsigned short* A2 = (unsigned short*)(sm + 166912);
  float* baseb  = (float*)(sm + 216064);
  float* logits = (float*)(sm + 412672);

  dim3 blk(256), blk5(512);
  TPtrs tp;
  tp.s[0] = wt1; tp.d[0] = wt1t;
  tp.s[1] = wt2; tp.d[1] = wt2t;
  tp.s[2] = wv1; tp.d[2] = wv1t;
  tp.s[3] = wv2; tp.d[3] = wv2t;
  tp.s[4] = wq1; tp.d[4] = wq1t;
  tp.s[5] = wp1;              tp.d[5] = wp1tt;
  tp.s[6] = wp1 + 1536 * D4_; tp.d[6] = wp1bt;
  tp.s[7] = wp2; tp.d[7] = wp2t;
  tp.s[8] = w_ih; tp.d[8] = wiht;
  tp.s[9] = w_hh; tp.d[9] = whht;

  // 1. transposes + softmax
  transpose_all_k<<<17857, blk, 0, stream>>>(tp, paras_score, score);
  // 2. pack all inputs into Acat + segment weights + zero vseg
  pack_segw_k<<<9958, blk, 0, stream>>>(video, a_buttons, para, a_texts, question,
                                        Acat, score, starts, ends, wseg, vseg);
  // 3. unified MLP layer 1 (26384 rows; rows<20992 use wv1 else wt1)
  gemmph<128,128,256,1,0,0><<<dim3(6, 207), blk, 0, stream>>>(
      Acat, wv1t, bv1, wt1t, bt1, 20992, Hid, D_, nullptr, 0, 0,
      nullptr, nullptr, nullptr, nullptr, 26384, D_, D_);
  // 4. unified MLP layer 2 (video rows -> atomic vseg; ab -> QAB; para/at/q -> Tout f32)
  gemmph<128,128,256,0,2,0><<<dim3(6, 207), blk, 0, stream>>>(
      Hid, wv2t, bv2, wt2t, bt2, 20992, nullptr, 0, nullptr, 0, 0,
      wseg, vseg, QAB, Tout, 26384, D_, D_);
  // 5. tseg
  tseg_k<<<48, blk, 0, stream>>>(Tout, score, tseg);
  // 6. QAB qa-half + A2
  qa_seg_k<<<1740, blk, 0, stream>>>(Tout, QAB, vseg, tseg, A2);
  // 7. baseb = A2 @ wp1_top + bp1
  gemmdb_f32<<<dim3(24, 1), blk, 0, stream>>>(A2, wp1tt, bp1, baseb, D4_, B_, D4_, 1536);
  // 8. hidp = relu(QAB @ wp1_bot + baseb[b])
  gemmph<256,256,512,1,0,1><<<dim3(12, 18), blk5, 0, stream>>>(
      QAB, wp1bt, baseb, wp1bt, baseb, 1 << 30, hidp, D4_, nullptr, 0, 0,
      nullptr, nullptr, nullptr, nullptr, RA_, D4_, 1536);
  // 9. xall = hidp @ wp2 + bp2
  gemmph<128,128,256,0,0,0><<<dim3(6, 36), blk, 0, stream>>>(
      hidp, wp2t, bp2, wp2t, bp2, 1 << 30, xall, D_, nullptr, 0, 0,
      nullptr, nullptr, nullptr, nullptr, RA_, D_, D4_);
  // 10. gather H (-> right after xall) + logits init
  gatherz_k<<<72, blk, 0, stream>>>(xall, label, state0, Hbf, bq2, logits);
  // 11. gi+gh merged: rows<4608 use w_ih -> gib, else w_hh -> ghb
  gemmph<128,128,256,0,0,0><<<dim3(18, 38), blk, 0, stream>>>(
      xall, wiht, b_ih, whht, b_hh, 4608, gib, G3_, ghb, G3_, 4608,
      nullptr, nullptr, nullptr, nullptr, 4800, G3_, D_);
  // 12. gates -> hnew
  gru_gates_k<<<1728, blk, 0, stream>>>(gib, ghb, Hbf, hnew);
  // 13. wq1 GEMM with fused logits
  gemmph<128,128,256,1,3,0><<<dim3(6, 36), blk, 0, stream>>>(
      hnew, wq1t, bq1, wq1t, bq1, 1 << 30, nullptr, 0, nullptr, 0, 0,
      wq2, logits, nullptr, nullptr, RA_, D_, D_);
  // 14. loss
  loss_k<<<1, blk, 0, stream>>>(logits, label, (float*)d_out);
}